// Round 6
// baseline (1129.368 us; speedup 1.0000x reference)
//
#include <hip/hip_runtime.h>
#include <hip/hip_bf16.h>

typedef __attribute__((ext_vector_type(8))) short short8;
typedef __attribute__((ext_vector_type(4))) float floatx4;
typedef unsigned short ushort_t;

__device__ inline float b2f(ushort_t s) {
    return __uint_as_float(((unsigned int)s) << 16);
}
__device__ inline ushort_t f2b(float f) {
    unsigned int u = __float_as_uint(f);
    unsigned int r = 0x7fff + ((u >> 16) & 1);
    return (ushort_t)((u + r) >> 16);
}
__device__ inline void load8(const float* p, float* f) {
    float4 a = *(const float4*)p;
    float4 b = *(const float4*)(p + 4);
    f[0] = a.x; f[1] = a.y; f[2] = a.z; f[3] = a.w;
    f[4] = b.x; f[5] = b.y; f[6] = b.z; f[7] = b.w;
}
__device__ inline void gload16(const ushort_t* g, ushort_t* l) {
    __builtin_amdgcn_global_load_lds(
        (const __attribute__((address_space(1))) unsigned int*)g,
        (__attribute__((address_space(3))) unsigned int*)l, 16, 0, 0);
}

// ---------- weight pre-pass: fp32 [K,N] -> bf16 [N,K] ----------
__global__ __launch_bounds__(256) void transpose_w(const float* __restrict__ src,
                                                   ushort_t* __restrict__ dst,
                                                   int K, int N) {
    __shared__ ushort_t tile[64][65];
    int kb = blockIdx.x * 64, nb = blockIdx.y * 64;
    int t = threadIdx.x;
#pragma unroll
    for (int i = 0; i < 4; ++i) {
        int r = (t >> 4) + i * 16;
        int c = (t & 15) * 4;
        float4 v = *(const float4*)(src + (size_t)(kb + r) * N + nb + c);
        tile[c + 0][r] = f2b(v.x);
        tile[c + 1][r] = f2b(v.y);
        tile[c + 2][r] = f2b(v.z);
        tile[c + 3][r] = f2b(v.w);
    }
    __syncthreads();
#pragma unroll
    for (int i = 0; i < 2; ++i) {
        int s = t + i * 256;
        int n = s >> 3, kc = (s & 7) * 8;
        ushort_t o[8];
#pragma unroll
        for (int j = 0; j < 8; ++j) o[j] = tile[n][kc + j];
        *(uint4*)(dst + (size_t)(nb + n) * K + kb + kc) = *(const uint4*)o;
    }
}

// ---------------- RMSNorm: fp32 in -> bf16 out ----------------
__global__ __launch_bounds__(256) void rmsnorm_kernel(const float* __restrict__ x,
                                                      const float* __restrict__ w,
                                                      ushort_t* __restrict__ out, int D) {
    int row = blockIdx.x;
    int t = threadIdx.x;
    const float* xr = x + (size_t)row * D;
    float f[8];
    load8(xr + t * 8, f);
    float ss = 0.f;
#pragma unroll
    for (int i = 0; i < 8; ++i) ss += f[i] * f[i];
#pragma unroll
    for (int m = 1; m < 64; m <<= 1) ss += __shfl_xor(ss, m);
    __shared__ float wsum[4];
    if ((t & 63) == 0) wsum[t >> 6] = ss;
    __syncthreads();
    float tot = wsum[0] + wsum[1] + wsum[2] + wsum[3];
    float r = rsqrtf(tot / (float)D + 1e-6f);
    float wf[8];
    load8(w + t * 8, wf);
    ushort_t o[8];
#pragma unroll
    for (int i = 0; i < 8; ++i) o[i] = f2b(f[i] * r * wf[i]);
    *(uint4*)(out + (size_t)row * D + t * 8) = *(const uint4*)o;
}

// ---------------- m97-structure GEMM (128x128, BK=32) ----------------
#define BM 128
#define BN 128
#define BK 32

template <int MODE, bool AUXF, bool OUTF, bool OUTT = false>
__global__ __launch_bounds__(256, 2) void gemm_bt(const ushort_t* __restrict__ A,
                                                  const ushort_t* __restrict__ Bt,
                                                  const void* __restrict__ AUXv,
                                                  void* __restrict__ Cv,
                                                  int M, int N, int K) {
    __shared__ __align__(16) ushort_t As[BM * BK];
    __shared__ __align__(16) ushort_t Bs[BN * BK];
    int t = threadIdx.x, wave = t >> 6, lane = t & 63;
    int l16 = lane & 15, l4 = lane >> 4;
    int bm = blockIdx.x * BM, bn = blockIdx.y * BN;
    int wm = (wave >> 1) * 64, wn = (wave & 1) * 64;
    floatx4 acc[4][4] = {};
    const ushort_t* gA = A + (size_t)(bm + wave * 32 + (lane >> 2)) * K + (lane & 3) * 8;
    const ushort_t* gB = Bt + (size_t)(bn + wave * 32 + (lane >> 2)) * K + (lane & 3) * 8;
    ushort_t* lA = As + wave * 32 * BK;
    ushort_t* lB = Bs + wave * 32 * BK;
    int ktiles = K / BK;
    for (int kt = 0; kt < ktiles; ++kt) {
        __syncthreads();
        int k0 = kt * BK;
        gload16(gA + k0, lA);
        gload16(gA + 16 * K + k0, lA + 16 * BK);
        gload16(gB + k0, lB);
        gload16(gB + 16 * K + k0, lB + 16 * BK);
        __syncthreads();
        short8 af[4], bf[4];
#pragma unroll
        for (int i = 0; i < 4; ++i)
            af[i] = *(const short8*)(As + (wm + i * 16 + l16) * BK + l4 * 8);
#pragma unroll
        for (int i = 0; i < 4; ++i)
            bf[i] = *(const short8*)(Bs + (wn + i * 16 + l16) * BK + l4 * 8);
#pragma unroll
        for (int mi = 0; mi < 4; ++mi)
#pragma unroll
            for (int ni = 0; ni < 4; ++ni)
                acc[mi][ni] = __builtin_amdgcn_mfma_f32_16x16x32_bf16(af[mi], bf[ni], acc[mi][ni], 0, 0, 0);
    }
#pragma unroll
    for (int mi = 0; mi < 4; ++mi)
#pragma unroll
        for (int ni = 0; ni < 4; ++ni)
#pragma unroll
            for (int r = 0; r < 4; ++r) {
                int row = bm + wm + mi * 16 + l4 * 4 + r;
                int col = bn + wn + ni * 16 + l16;
                size_t idx = (size_t)row * N + col;
                float v = acc[mi][ni][r];
                if (MODE == 1) {
                    float a = AUXF ? ((const float*)AUXv)[idx] : b2f(((const ushort_t*)AUXv)[idx]);
                    v += a;
                }
                if (MODE == 2) {
                    float h = AUXF ? ((const float*)AUXv)[idx] : b2f(((const ushort_t*)AUXv)[idx]);
                    v = (h / (1.f + __expf(-h))) * v;
                }
                if (OUTT) ((ushort_t*)Cv)[(size_t)col * M + row] = f2b(v);
                else if (OUTF) ((float*)Cv)[idx] = v;
                else ((ushort_t*)Cv)[idx] = f2b(v);
            }
}

// ---------------- 256x256 8-phase GEMM (BK=64, 8 waves, st_16x32 swizzle) ----------------
// MODE 0: C = AB ; MODE 2: C = silu(AUX) * AB.  All bf16.
__device__ inline void vm6() { asm volatile("s_waitcnt vmcnt(6)" ::: "memory"); }

template <int MODE>
__global__ __launch_bounds__(512, 2) void gemm8(const ushort_t* __restrict__ A,
                                                const ushort_t* __restrict__ Bt,
                                                const ushort_t* AUX,
                                                ushort_t* C,
                                                int M, int N, int K) {
    __shared__ __align__(16) ushort_t Lds[2 * 32768];   // 128 KiB: 2 slots x (A 32KB + B 32KB)
    const int tid = threadIdx.x;
    const int wv = tid >> 6, lane = tid & 63;
    const int l16 = lane & 15, l4 = lane >> 4;
    const int wr = wv >> 2, wc = wv & 3;
    // XCD-aware block swizzle (nwg % 8 == 0)
    int nwg = gridDim.x;
    int per = nwg >> 3;
    int wg = (blockIdx.x & 7) * per + (blockIdx.x >> 3);
    int mtiles = M >> 8;
    int bx = wg & (mtiles - 1);
    int by = wg / mtiles;
    int bm = bx << 8, bn = by << 8;

    // staging: chunk = 64 rows x 64 shorts; thread -> dest row sr=tid>>3, col (tid&7)*8 (linear LDS)
    // global source col inverse-swizzled: flip 16 shorts when (row&4)  [st_16x32]
    const int sr = tid >> 3;
    const int scol = ((tid & 7) << 3) ^ ((sr & 4) << 2);
    const ushort_t* gA = A + (size_t)(bm + sr) * K + scol;
    const ushort_t* gB = Bt + (size_t)(bn + sr) * K + scol;
    ushort_t* ldsw = Lds + wv * 512;  // wave-uniform dest base (hw adds lane*16B)

    const int ktiles = K >> 6;
    const int niter = ktiles >> 1;
    const int km = ktiles - 1;

#define STG_A(slot, j, kt) gload16(gA + (size_t)((j) * 64) * K + ((kt) << 6), ldsw + (slot) * 32768 + (j) * 4096)
#define STG_B(slot, j, kt) gload16(gB + (size_t)((j) * 64) * K + ((kt) << 6), ldsw + (slot) * 32768 + 16384 + (j) * 4096)

    // prologue: tile0 -> slot0 (8 chunks), tile1 -> slot1 (6 chunks; a1,a3 staged in ph1)
    STG_A(0, 0, 0); STG_A(0, 2, 0); STG_A(0, 1, 0); STG_A(0, 3, 0);
    STG_B(0, 0, 0); STG_B(0, 1, 0); STG_B(0, 2, 0); STG_B(0, 3, 0);
    STG_A(1, 0, 1); STG_A(1, 2, 1);
    STG_B(1, 0, 1); STG_B(1, 1, 1); STG_B(1, 2, 1); STG_B(1, 3, 1);
    vm6();  // first 8 (tile0) landed
    asm volatile("" ::: "memory");
    __builtin_amdgcn_s_barrier();

    // swizzled ds_read column (same involution as source)
    const int sc = (l4 << 3) ^ ((l16 & 4) << 2);
    const int aoff = (wr * 128 + l16) * 64 + sc;
    const int boff = (wc * 64 + l16) * 64 + sc;
    floatx4 acc[8][4] = {};
    short8 aR[4][2], bR[4][2];

#define DSA(slot, mh) { _Pragma("unroll") for (int m = 0; m < 4; ++m) { \
    _Pragma("unroll") for (int kk = 0; kk < 2; ++kk) \
      aR[m][kk] = *(const short8*)(Lds + (slot) * 32768 + aoff + ((mh) * 64 + m * 16) * 64 + kk * 32); } }
#define DSB(slot, nh) { _Pragma("unroll") for (int n = 0; n < 2; ++n) { \
    _Pragma("unroll") for (int kk = 0; kk < 2; ++kk) \
      bR[(nh) * 2 + n][kk] = *(const short8*)(Lds + (slot) * 32768 + 16384 + boff + (((nh) * 2 + n) * 16) * 64 + kk * 32); } }
#define QUAD(mh, nlo) { _Pragma("unroll") for (int m = 0; m < 4; ++m) \
    _Pragma("unroll") for (int n = 0; n < 2; ++n) \
    _Pragma("unroll") for (int kk = 0; kk < 2; ++kk) \
      acc[(mh) * 4 + m][(nlo) + n] = __builtin_amdgcn_mfma_f32_16x16x32_bf16( \
          aR[m][kk], bR[(nlo) + n][kk], acc[(mh) * 4 + m][(nlo) + n], 0, 0, 0); }
#define PHASE(DS, ST, MH, NLO, VM) { \
    DS; ST; \
    asm volatile("" ::: "memory"); \
    __builtin_amdgcn_s_barrier(); \
    asm volatile("s_waitcnt lgkmcnt(0)" ::: "memory"); \
    __builtin_amdgcn_sched_barrier(0); \
    __builtin_amdgcn_s_setprio(1); \
    QUAD(MH, NLO); \
    __builtin_amdgcn_s_setprio(0); \
    VM; \
    asm volatile("" ::: "memory"); \
    __builtin_amdgcn_s_barrier(); }

    for (int it = 0; it < niter; ++it) {
        int t1 = 2 * it + 1;
        int t2 = (2 * it + 2) & km;
        int t3 = (2 * it + 3) & km;
        PHASE({ DSA(0, 0); DSB(0, 0); }, { STG_A(1, 1, t1); STG_A(1, 3, t1); }, 0, 0, );
        PHASE({ DSB(0, 1); },            { STG_A(0, 0, t2); STG_A(0, 2, t2); }, 0, 2, );
        PHASE({ DSA(0, 1); },            { STG_B(0, 0, t2); STG_B(0, 1, t2); }, 1, 2, );
        PHASE({ },                       { STG_B(0, 2, t2); STG_B(0, 3, t2); }, 1, 0, vm6(); );
        PHASE({ DSA(1, 0); DSB(1, 0); }, { STG_A(0, 1, t2); STG_A(0, 3, t2); }, 0, 0, );
        PHASE({ DSB(1, 1); },            { STG_A(1, 0, t3); STG_A(1, 2, t3); }, 0, 2, );
        PHASE({ DSA(1, 1); },            { STG_B(1, 0, t3); STG_B(1, 1, t3); }, 1, 2, );
        PHASE({ },                       { STG_B(1, 2, t3); STG_B(1, 3, t3); }, 1, 0, vm6(); );
    }

    // epilogue
#pragma unroll
    for (int mi = 0; mi < 8; ++mi)
#pragma unroll
        for (int ni = 0; ni < 4; ++ni)
#pragma unroll
            for (int r = 0; r < 4; ++r) {
                int row = bm + wr * 128 + mi * 16 + l4 * 4 + r;
                int col = bn + wc * 64 + ni * 16 + l16;
                size_t idx = (size_t)row * N + col;
                float v = acc[mi][ni][r];
                if (MODE == 2) {
                    float h = b2f(AUX[idx]);
                    v = (h / (1.f + __expf(-h))) * v;
                }
                C[idx] = f2b(v);
            }
#undef STG_A
#undef STG_B
#undef DSA
#undef DSB
#undef QUAD
#undef PHASE
}

// ---------------- Flash attention (causal, GQA), QB=128, SB=64 ----------------
#define QB 128
#define SB 64

__global__ __launch_bounds__(256, 2) void attn_kernel(const ushort_t* __restrict__ Q,
                                                      const ushort_t* __restrict__ Kb,
                                                      const ushort_t* __restrict__ VbT,
                                                      ushort_t* __restrict__ O, int Tlen) {
    const int D = 2048, KVD = 512, dh = 128;
    const int MTOK = 4096;
    int qt = blockIdx.x, h = blockIdx.y, b = blockIdx.z;
    int kv = h >> 2;
    int t = threadIdx.x, wave = t >> 6, lane = t & 63;
    int l16 = lane & 15, l4 = lane >> 4;
    __shared__ __align__(16) ushort_t Ks[SB][dh + 8];
    __shared__ __align__(16) ushort_t Vt[dh][SB + 8];
    __shared__ __align__(16) ushort_t Ps[8][16][SB + 8];
    int qbase = qt * QB;
    int qfrag = qbase + wave * 32;
    short8 qf[2][4];
#pragma unroll
    for (int f = 0; f < 2; ++f) {
        const ushort_t* Qrow = Q + ((size_t)(b * Tlen) + qfrag + f * 16 + l16) * D + h * dh;
#pragma unroll
        for (int kk = 0; kk < 4; ++kk) qf[f][kk] = *(const short8*)(Qrow + kk * 32 + l4 * 8);
    }
    floatx4 o_acc[2][8] = {};
    float m_r[2][4], l_r[2][4];
#pragma unroll
    for (int f = 0; f < 2; ++f)
#pragma unroll
        for (int r = 0; r < 4; ++r) { m_r[f][r] = -INFINITY; l_r[f][r] = 0.f; }
    const float scale = 0.08838834764831845f;
    int nst = (qbase + QB) / SB;
    const ushort_t* Kg = Kb + ((size_t)(b * Tlen) + (t >> 4)) * KVD + kv * dh + (t & 15) * 8;
    const ushort_t* Vg = VbT + (size_t)(kv * dh + (t >> 3)) * MTOK + b * Tlen + (t & 7) * 8;
    uint4 kreg[4], vreg[4];
#pragma unroll
    for (int p = 0; p < 4; ++p) {
        kreg[p] = *(const uint4*)(Kg + (size_t)(p * 16) * KVD);
        vreg[p] = *(const uint4*)(Vg + (size_t)(p * 32) * MTOK);
    }
    for (int st = 0; st < nst; ++st) {
        __syncthreads();
#pragma unroll
        for (int p = 0; p < 4; ++p) {
            *(uint4*)(&Ks[(t >> 4) + p * 16][(t & 15) * 8]) = kreg[p];
            *(uint4*)(&Vt[(t >> 3) + p * 32][(t & 7) * 8]) = vreg[p];
        }
        __syncthreads();
        if (st + 1 < nst) {
            size_t off = (size_t)(st + 1) * SB;
#pragma unroll
            for (int p = 0; p < 4; ++p) {
                kreg[p] = *(const uint4*)(Kg + (off + p * 16) * KVD);
                vreg[p] = *(const uint4*)(Vg + (size_t)(p * 32) * MTOK + off);
            }
        }
        int s0 = st * SB;
        if (s0 < qfrag + 32) {
            floatx4 sa[2][4] = {};
            __builtin_amdgcn_s_setprio(1);
#pragma unroll
            for (int ss = 0; ss < 4; ++ss)
#pragma unroll
                for (int kk = 0; kk < 4; ++kk) {
                    short8 kf = *(const short8*)(&Ks[ss * 16 + l16][kk * 32 + l4 * 8]);
                    sa[0][ss] = __builtin_amdgcn_mfma_f32_16x16x32_bf16(qf[0][kk], kf, sa[0][ss], 0, 0, 0);
                    sa[1][ss] = __builtin_amdgcn_mfma_f32_16x16x32_bf16(qf[1][kk], kf, sa[1][ss], 0, 0, 0);
                }
            __builtin_amdgcn_s_setprio(0);
#pragma unroll
            for (int f = 0; f < 2; ++f) {
                float sv[4][4], pmax[4];
#pragma unroll
                for (int r = 0; r < 4; ++r) pmax[r] = -INFINITY;
#pragma unroll
                for (int ss = 0; ss < 4; ++ss) {
                    int scol = s0 + ss * 16 + l16;
#pragma unroll
                    for (int r = 0; r < 4; ++r) {
                        int qrow = qfrag + f * 16 + l4 * 4 + r;
                        float v = sa[f][ss][r] * scale;
                        if (scol > qrow) v = -INFINITY;
                        sv[ss][r] = v;
                        pmax[r] = fmaxf(pmax[r], v);
                    }
                }
#pragma unroll
                for (int m = 1; m < 16; m <<= 1)
#pragma unroll
                    for (int r = 0; r < 4; ++r) pmax[r] = fmaxf(pmax[r], __shfl_xor(pmax[r], m));
                float esc[4], rsum[4];
#pragma unroll
                for (int r = 0; r < 4; ++r) {
                    float mn = fmaxf(m_r[f][r], pmax[r]);
                    esc[r] = __expf(m_r[f][r] - mn);
                    float rs = 0.f;
#pragma unroll
                    for (int ss = 0; ss < 4; ++ss) {
                        float p = __expf(sv[ss][r] - mn);
                        sv[ss][r] = p;
                        rs += p;
                    }
                    rsum[r] = rs;
                    m_r[f][r] = mn;
                }
#pragma unroll
                for (int m = 1; m < 16; m <<= 1)
#pragma unroll
                    for (int r = 0; r < 4; ++r) rsum[r] += __shfl_xor(rsum[r], m);
#pragma unroll
                for (int r = 0; r < 4; ++r) l_r[f][r] = l_r[f][r] * esc[r] + rsum[r];
#pragma unroll
                for (int c = 0; c < 8; ++c)
#pragma unroll
                    for (int r = 0; r < 4; ++r) o_acc[f][c][r] *= esc[r];
#pragma unroll
                for (int ss = 0; ss < 4; ++ss)
#pragma unroll
                    for (int r = 0; r < 4; ++r)
                        Ps[wave * 2 + f][l4 * 4 + r][ss * 16 + l16] = f2b(sv[ss][r]);
            }
            short8 pa[2][2];
#pragma unroll
            for (int f = 0; f < 2; ++f)
#pragma unroll
                for (int kk = 0; kk < 2; ++kk)
                    pa[f][kk] = *(const short8*)(&Ps[wave * 2 + f][l16][kk * 32 + l4 * 8]);
            __builtin_amdgcn_s_setprio(1);
#pragma unroll
            for (int c = 0; c < 8; ++c)
#pragma unroll
                for (int kk = 0; kk < 2; ++kk) {
                    short8 vf = *(const short8*)(&Vt[c * 16 + l16][kk * 32 + l4 * 8]);
                    o_acc[0][c] = __builtin_amdgcn_mfma_f32_16x16x32_bf16(pa[0][kk], vf, o_acc[0][c], 0, 0, 0);
                    o_acc[1][c] = __builtin_amdgcn_mfma_f32_16x16x32_bf16(pa[1][kk], vf, o_acc[1][c], 0, 0, 0);
                }
            __builtin_amdgcn_s_setprio(0);
        }
    }
#pragma unroll
    for (int f = 0; f < 2; ++f)
#pragma unroll
        for (int c = 0; c < 8; ++c)
#pragma unroll
            for (int r = 0; r < 4; ++r) {
                int qrow = qfrag + f * 16 + l4 * 4 + r;
                int col = h * dh + c * 16 + l16;
                O[((size_t)(b * Tlen) + qrow) * D + col] = f2b(o_acc[f][c][r] / l_r[f][r]);
            }
}

extern "C" void kernel_launch(void* const* d_in, const int* in_sizes, int n_in,
                              void* d_out, int out_size, void* d_ws, size_t ws_size,
                              hipStream_t stream) {
    const float* x   = (const float*)d_in[0];
    const float* n1w = (const float*)d_in[1];
    const float* n2w = (const float*)d_in[2];
    const float* Wq  = (const float*)d_in[3];
    const float* Wk  = (const float*)d_in[4];
    const float* Wv  = (const float*)d_in[5];
    const float* Wo  = (const float*)d_in[6];
    const float* Wc  = (const float*)d_in[7];
    const float* W1  = (const float*)d_in[8];
    const float* W2  = (const float*)d_in[9];
    const float* W3  = (const float*)d_in[10];
    float* out = (float*)d_out;

    const int B = 2, T = 2048, D = 2048, F = 8192, KVD = 512;
    const int M = B * T;  // 4096
    const size_t XD   = (size_t)M * D * 2;
    const size_t XDF  = (size_t)M * D * 4;
    const size_t KVSZ = (size_t)M * KVD * 2;
    const size_t MF   = (size_t)M * F * 2;
    const size_t WDD  = (size_t)D * D * 2;
    const size_t WDK  = (size_t)D * KVD * 2;
    const size_t WDF  = (size_t)D * F * 2;

    char* w = (char*)d_ws;
    ushort_t* xn    = (ushort_t*)(w);
    ushort_t* qtmp  = (ushort_t*)(w + XD);
    ushort_t* qfin  = (ushort_t*)(w + 2 * XD);
    float*    x2f   = (float*)   (w + 3 * XD);
    ushort_t* kbuf  = (ushort_t*)(w + 3 * XD + XDF);
    ushort_t* vbufT = (ushort_t*)(w + 3 * XD + XDF + KVSZ);
    ushort_t* h1    = (ushort_t*)(w + 3 * XD + XDF + 2 * KVSZ);
    char* wt = w + 3 * XD + XDF + 2 * KVSZ + MF;
    ushort_t* WqT = (ushort_t*)(wt);
    ushort_t* WcT = (ushort_t*)(wt + WDD);
    ushort_t* WoT = (ushort_t*)(wt + 2 * WDD);
    ushort_t* WkT = (ushort_t*)(wt + 3 * WDD);
    ushort_t* WvT = (ushort_t*)(wt + 3 * WDD + WDK);
    ushort_t* W1T = (ushort_t*)(wt + 3 * WDD + 2 * WDK);
    ushort_t* W3T = (ushort_t*)(wt + 3 * WDD + 2 * WDK + WDF);
    ushort_t* W2T = (ushort_t*)(wt + 3 * WDD + 2 * WDK + 2 * WDF);

    dim3 blk(256);

    transpose_w<<<dim3(D / 64, D / 64), blk, 0, stream>>>(Wq, WqT, D, D);
    transpose_w<<<dim3(D / 64, D / 64), blk, 0, stream>>>(Wc, WcT, D, D);
    transpose_w<<<dim3(D / 64, D / 64), blk, 0, stream>>>(Wo, WoT, D, D);
    transpose_w<<<dim3(D / 64, KVD / 64), blk, 0, stream>>>(Wk, WkT, D, KVD);
    transpose_w<<<dim3(D / 64, KVD / 64), blk, 0, stream>>>(Wv, WvT, D, KVD);
    transpose_w<<<dim3(D / 64, F / 64), blk, 0, stream>>>(W1, W1T, D, F);
    transpose_w<<<dim3(D / 64, F / 64), blk, 0, stream>>>(W3, W3T, D, F);
    transpose_w<<<dim3(F / 64, D / 64), blk, 0, stream>>>(W2, W2T, F, D);

    rmsnorm_kernel<<<M, blk, 0, stream>>>(x, n1w, xn, D);
    gemm_bt<0, false, false><<<dim3(M / BM, D / BN), blk, 0, stream>>>(xn, WqT, nullptr, qtmp, M, D, D);
    gemm_bt<1, false, false><<<dim3(M / BM, D / BN), blk, 0, stream>>>(qtmp, WcT, qtmp, qfin, M, D, D);
    gemm_bt<0, false, false><<<dim3(M / BM, KVD / BN), blk, 0, stream>>>(xn, WkT, nullptr, kbuf, M, KVD, D);
    gemm_bt<0, false, false, true><<<dim3(M / BM, KVD / BN), blk, 0, stream>>>(xn, WvT, nullptr, vbufT, M, KVD, D);
    attn_kernel<<<dim3(T / QB, 16, B), blk, 0, stream>>>(qfin, kbuf, vbufT, qtmp, T);
    gemm_bt<1, true, true><<<dim3(M / BM, D / BN), blk, 0, stream>>>(qtmp, WoT, x, x2f, M, D, D);
    rmsnorm_kernel<<<M, blk, 0, stream>>>(x2f, n2w, xn, D);
    // MLP: h1 = xn2 @ W1 ; h1 = silu(h1) * (xn2 @ W3)   [256^2 8-phase kernels]
    gemm8<0><<<dim3((M / 256) * (F / 256)), dim3(512), 0, stream>>>(xn, W1T, nullptr, h1, M, F, D);
    gemm8<2><<<dim3((M / 256) * (F / 256)), dim3(512), 0, stream>>>(xn, W3T, h1, h1, M, F, D);
    gemm_bt<1, true, true><<<dim3(M / BM, D / BN), blk, 0, stream>>>(h1, W2T, x2f, out, M, D, F);
}

// Round 7
// 1053.307 us; speedup vs baseline: 1.0722x; 1.0722x over previous
//
#include <hip/hip_runtime.h>
#include <hip/hip_bf16.h>

typedef __attribute__((ext_vector_type(8))) short short8;
typedef __attribute__((ext_vector_type(4))) float floatx4;
typedef unsigned short ushort_t;

__device__ inline float b2f(ushort_t s) {
    return __uint_as_float(((unsigned int)s) << 16);
}
__device__ inline ushort_t f2b(float f) {
    unsigned int u = __float_as_uint(f);
    unsigned int r = 0x7fff + ((u >> 16) & 1);
    return (ushort_t)((u + r) >> 16);
}
__device__ inline void load8(const float* p, float* f) {
    float4 a = *(const float4*)p;
    float4 b = *(const float4*)(p + 4);
    f[0] = a.x; f[1] = a.y; f[2] = a.z; f[3] = a.w;
    f[4] = b.x; f[5] = b.y; f[6] = b.z; f[7] = b.w;
}
__device__ inline void gload16(const ushort_t* g, ushort_t* l) {
    __builtin_amdgcn_global_load_lds(
        (const __attribute__((address_space(1))) unsigned int*)g,
        (__attribute__((address_space(3))) unsigned int*)l, 16, 0, 0);
}

// ---------- weight pre-pass: fp32 [K,N] -> bf16 [N,K] ----------
__global__ __launch_bounds__(256) void transpose_w(const float* __restrict__ src,
                                                   ushort_t* __restrict__ dst,
                                                   int K, int N) {
    __shared__ ushort_t tile[64][65];
    int kb = blockIdx.x * 64, nb = blockIdx.y * 64;
    int t = threadIdx.x;
#pragma unroll
    for (int i = 0; i < 4; ++i) {
        int r = (t >> 4) + i * 16;
        int c = (t & 15) * 4;
        float4 v = *(const float4*)(src + (size_t)(kb + r) * N + nb + c);
        tile[c + 0][r] = f2b(v.x);
        tile[c + 1][r] = f2b(v.y);
        tile[c + 2][r] = f2b(v.z);
        tile[c + 3][r] = f2b(v.w);
    }
    __syncthreads();
#pragma unroll
    for (int i = 0; i < 2; ++i) {
        int s = t + i * 256;
        int n = s >> 3, kc = (s & 7) * 8;
        ushort_t o[8];
#pragma unroll
        for (int j = 0; j < 8; ++j) o[j] = tile[n][kc + j];
        *(uint4*)(dst + (size_t)(nb + n) * K + kb + kc) = *(const uint4*)o;
    }
}

// ---------------- RMSNorm: fp32 in -> bf16 out ----------------
__global__ __launch_bounds__(256) void rmsnorm_kernel(const float* __restrict__ x,
                                                      const float* __restrict__ w,
                                                      ushort_t* __restrict__ out, int D) {
    int row = blockIdx.x;
    int t = threadIdx.x;
    const float* xr = x + (size_t)row * D;
    float f[8];
    load8(xr + t * 8, f);
    float ss = 0.f;
#pragma unroll
    for (int i = 0; i < 8; ++i) ss += f[i] * f[i];
#pragma unroll
    for (int m = 1; m < 64; m <<= 1) ss += __shfl_xor(ss, m);
    __shared__ float wsum[4];
    if ((t & 63) == 0) wsum[t >> 6] = ss;
    __syncthreads();
    float tot = wsum[0] + wsum[1] + wsum[2] + wsum[3];
    float r = rsqrtf(tot / (float)D + 1e-6f);
    float wf[8];
    load8(w + t * 8, wf);
    ushort_t o[8];
#pragma unroll
    for (int i = 0; i < 8; ++i) o[i] = f2b(f[i] * r * wf[i]);
    *(uint4*)(out + (size_t)row * D + t * 8) = *(const uint4*)o;
}

// ---------------- m97-structure GEMM (128x128, BK=32) ----------------
#define BM 128
#define BN 128
#define BK 32

template <int MODE, bool AUXF, bool OUTF, bool OUTT = false>
__global__ __launch_bounds__(256, 2) void gemm_bt(const ushort_t* __restrict__ A,
                                                  const ushort_t* __restrict__ Bt,
                                                  const void* __restrict__ AUXv,
                                                  void* __restrict__ Cv,
                                                  int M, int N, int K) {
    __shared__ __align__(16) ushort_t As[BM * BK];
    __shared__ __align__(16) ushort_t Bs[BN * BK];
    int t = threadIdx.x, wave = t >> 6, lane = t & 63;
    int l16 = lane & 15, l4 = lane >> 4;
    int bm = blockIdx.x * BM, bn = blockIdx.y * BN;
    int wm = (wave >> 1) * 64, wn = (wave & 1) * 64;
    floatx4 acc[4][4] = {};
    const ushort_t* gA = A + (size_t)(bm + wave * 32 + (lane >> 2)) * K + (lane & 3) * 8;
    const ushort_t* gB = Bt + (size_t)(bn + wave * 32 + (lane >> 2)) * K + (lane & 3) * 8;
    ushort_t* lA = As + wave * 32 * BK;
    ushort_t* lB = Bs + wave * 32 * BK;
    int ktiles = K / BK;
    for (int kt = 0; kt < ktiles; ++kt) {
        __syncthreads();
        int k0 = kt * BK;
        gload16(gA + k0, lA);
        gload16(gA + 16 * K + k0, lA + 16 * BK);
        gload16(gB + k0, lB);
        gload16(gB + 16 * K + k0, lB + 16 * BK);
        __syncthreads();
        short8 af[4], bf[4];
#pragma unroll
        for (int i = 0; i < 4; ++i)
            af[i] = *(const short8*)(As + (wm + i * 16 + l16) * BK + l4 * 8);
#pragma unroll
        for (int i = 0; i < 4; ++i)
            bf[i] = *(const short8*)(Bs + (wn + i * 16 + l16) * BK + l4 * 8);
#pragma unroll
        for (int mi = 0; mi < 4; ++mi)
#pragma unroll
            for (int ni = 0; ni < 4; ++ni)
                acc[mi][ni] = __builtin_amdgcn_mfma_f32_16x16x32_bf16(af[mi], bf[ni], acc[mi][ni], 0, 0, 0);
    }
#pragma unroll
    for (int mi = 0; mi < 4; ++mi)
#pragma unroll
        for (int ni = 0; ni < 4; ++ni)
#pragma unroll
            for (int r = 0; r < 4; ++r) {
                int row = bm + wm + mi * 16 + l4 * 4 + r;
                int col = bn + wn + ni * 16 + l16;
                size_t idx = (size_t)row * N + col;
                float v = acc[mi][ni][r];
                if (MODE == 1) {
                    float a = AUXF ? ((const float*)AUXv)[idx] : b2f(((const ushort_t*)AUXv)[idx]);
                    v += a;
                }
                if (MODE == 2) {
                    float h = AUXF ? ((const float*)AUXv)[idx] : b2f(((const ushort_t*)AUXv)[idx]);
                    v = (h / (1.f + __expf(-h))) * v;
                }
                if (OUTT) ((ushort_t*)Cv)[(size_t)col * M + row] = f2b(v);
                else if (OUTF) ((float*)Cv)[idx] = v;
                else ((ushort_t*)Cv)[idx] = f2b(v);
            }
}

// ---------------- 256x256 8-phase GEMM (BK=64, 8 waves, XOR-8 swizzle) ----------------
// MODE 0: C = AB ; MODE 2: C = silu(AUX) * AB.  All bf16.
__device__ inline void vm6() { asm volatile("s_waitcnt vmcnt(6)" ::: "memory"); }

template <int MODE>
__global__ __launch_bounds__(512, 2) void gemm8(const ushort_t* __restrict__ A,
                                                const ushort_t* __restrict__ Bt,
                                                const ushort_t* AUX,
                                                ushort_t* C,
                                                int M, int N, int K) {
    __shared__ __align__(16) ushort_t Lds[2 * 32768];   // 128 KiB: 2 slots x (A 32KB + B 32KB)
    const int tid = threadIdx.x;
    const int wv = tid >> 6, lane = tid & 63;
    const int l16 = lane & 15, l4 = lane >> 4;
    const int wr = wv >> 2, wc = wv & 3;
    // XCD-aware block swizzle (nwg % 8 == 0)
    int nwg = gridDim.x;
    int per = nwg >> 3;
    int wg = (blockIdx.x & 7) * per + (blockIdx.x >> 3);
    int mtiles = M >> 8;
    int bx = wg & (mtiles - 1);
    int by = wg / mtiles;
    int bm = bx << 8, bn = by << 8;

    // staging: chunk = 64 rows x 64 shorts. LDS dest is linear (row=tid>>3, phys_slot=tid&7);
    // global source column is inverse-XOR-8 swizzled: logical_slot = phys_slot ^ (row&7)
    const int sr = tid >> 3;
    const int scol = (((tid & 7) ^ (sr & 7)) << 3);
    const ushort_t* gA = A + (size_t)(bm + sr) * K + scol;
    const ushort_t* gB = Bt + (size_t)(bn + sr) * K + scol;
    ushort_t* ldsw = Lds + wv * 512;  // wave-uniform dest base (hw adds lane*16B)

    const int ktiles = K >> 6;
    const int niter = ktiles >> 1;
    const int km = ktiles - 1;

#define STG_A(slot, j, kt) gload16(gA + (size_t)((j) * 64) * K + ((kt) << 6), ldsw + (slot) * 32768 + (j) * 4096)
#define STG_B(slot, j, kt) gload16(gB + (size_t)((j) * 64) * K + ((kt) << 6), ldsw + (slot) * 32768 + 16384 + (j) * 4096)

    // prologue: tile0 -> slot0 (8 chunks), tile1 -> slot1 (6 chunks; a1,a3 staged in ph1)
    STG_A(0, 0, 0); STG_A(0, 2, 0); STG_A(0, 1, 0); STG_A(0, 3, 0);
    STG_B(0, 0, 0); STG_B(0, 1, 0); STG_B(0, 2, 0); STG_B(0, 3, 0);
    STG_A(1, 0, 1); STG_A(1, 2, 1);
    STG_B(1, 0, 1); STG_B(1, 1, 1); STG_B(1, 2, 1); STG_B(1, 3, 1);
    vm6();  // first 8 (tile0) landed
    asm volatile("" ::: "memory");
    __builtin_amdgcn_s_barrier();

    // ds_read: logical slot s = kk*4 + l4, physical = s ^ (row&7), row&7 = l16&7
    const int lx = l4 ^ (l16 & 7);           // physslot(kk) = lx ^ (kk<<2)
    floatx4 acc[8][4] = {};
    short8 aR[4][2], bR[4][2];

#define DSA(slot, mh) { _Pragma("unroll") for (int m = 0; m < 4; ++m) { \
    _Pragma("unroll") for (int kk = 0; kk < 2; ++kk) \
      aR[m][kk] = *(const short8*)(Lds + (slot) * 32768 + \
          (wr * 128 + (mh) * 64 + m * 16 + l16) * 64 + ((lx ^ (kk << 2)) << 3)); } }
#define DSB(slot, nh) { _Pragma("unroll") for (int n = 0; n < 2; ++n) { \
    _Pragma("unroll") for (int kk = 0; kk < 2; ++kk) \
      bR[(nh) * 2 + n][kk] = *(const short8*)(Lds + (slot) * 32768 + 16384 + \
          (wc * 64 + ((nh) * 2 + n) * 16 + l16) * 64 + ((lx ^ (kk << 2)) << 3)); } }
#define QUAD(mh, nlo) { _Pragma("unroll") for (int m = 0; m < 4; ++m) \
    _Pragma("unroll") for (int n = 0; n < 2; ++n) \
    _Pragma("unroll") for (int kk = 0; kk < 2; ++kk) \
      acc[(mh) * 4 + m][(nlo) + n] = __builtin_amdgcn_mfma_f32_16x16x32_bf16( \
          aR[m][kk], bR[(nlo) + n][kk], acc[(mh) * 4 + m][(nlo) + n], 0, 0, 0); }
#define PHASE(DS, ST, MH, NLO, VM) { \
    DS; ST; \
    asm volatile("" ::: "memory"); \
    __builtin_amdgcn_s_barrier(); \
    asm volatile("s_waitcnt lgkmcnt(0)" ::: "memory"); \
    __builtin_amdgcn_sched_barrier(0); \
    __builtin_amdgcn_s_setprio(1); \
    QUAD(MH, NLO); \
    __builtin_amdgcn_s_setprio(0); \
    VM; \
    asm volatile("" ::: "memory"); \
    __builtin_amdgcn_s_barrier(); }

    for (int it = 0; it < niter; ++it) {
        int t1 = 2 * it + 1;
        int t2 = (2 * it + 2) & km;
        int t3 = (2 * it + 3) & km;
        PHASE({ DSA(0, 0); DSB(0, 0); }, { STG_A(1, 1, t1); STG_A(1, 3, t1); }, 0, 0, );
        PHASE({ DSB(0, 1); },            { STG_A(0, 0, t2); STG_A(0, 2, t2); }, 0, 2, );
        PHASE({ DSA(0, 1); },            { STG_B(0, 0, t2); STG_B(0, 1, t2); }, 1, 2, );
        PHASE({ },                       { STG_B(0, 2, t2); STG_B(0, 3, t2); }, 1, 0, vm6(); );
        PHASE({ DSA(1, 0); DSB(1, 0); }, { STG_A(0, 1, t2); STG_A(0, 3, t2); }, 0, 0, );
        PHASE({ DSB(1, 1); },            { STG_A(1, 0, t3); STG_A(1, 2, t3); }, 0, 2, );
        PHASE({ DSA(1, 1); },            { STG_B(1, 0, t3); STG_B(1, 1, t3); }, 1, 2, );
        PHASE({ },                       { STG_B(1, 2, t3); STG_B(1, 3, t3); }, 1, 0, vm6(); );
    }

    // epilogue
#pragma unroll
    for (int mi = 0; mi < 8; ++mi)
#pragma unroll
        for (int ni = 0; ni < 4; ++ni)
#pragma unroll
            for (int r = 0; r < 4; ++r) {
                int row = bm + wr * 128 + mi * 16 + l4 * 4 + r;
                int col = bn + wc * 64 + ni * 16 + l16;
                size_t idx = (size_t)row * N + col;
                float v = acc[mi][ni][r];
                if (MODE == 2) {
                    float h = b2f(AUX[idx]);
                    v = (h / (1.f + __expf(-h))) * v;
                }
                C[idx] = f2b(v);
            }
#undef STG_A
#undef STG_B
#undef DSA
#undef DSB
#undef QUAD
#undef PHASE
}

// ---------------- Flash attention (causal, GQA), QB=64, SB=64, causal-balanced pairs ----------------
// grid: (16 pairs, N_HEADS, B). block 256 = 4 waves; wave owns 16 q rows.
// Each block handles q-tiles (31-p) then p: 33 steps total -> perfectly balanced.
#define QB 64
#define SB 64

__global__ __launch_bounds__(256, 2) void attn_kernel(const ushort_t* __restrict__ Q,
                                                      const ushort_t* __restrict__ Kb,
                                                      const ushort_t* __restrict__ VbT,
                                                      ushort_t* __restrict__ O, int Tlen) {
    const int D = 2048, KVD = 512, dh = 128;
    const int MTOK = 4096;
    int p = blockIdx.x, h = blockIdx.y, b = blockIdx.z;
    int kv = h >> 2;
    int t = threadIdx.x, wave = t >> 6, lane = t & 63;
    int l16 = lane & 15, l4 = lane >> 4;
    __shared__ __align__(16) ushort_t Ks[SB][dh + 8];      // 17.4 KB
    __shared__ __align__(16) ushort_t Vt[dh][SB + 8];      // 18.4 KB
    __shared__ __align__(16) ushort_t Ps[4][16][SB + 8];   //  9.2 KB
    const float scale = 0.08838834764831845f;
    const ushort_t* Kg = Kb + ((size_t)(b * Tlen) + (t >> 4)) * KVD + kv * dh + (t & 15) * 8;
    const ushort_t* Vg = VbT + (size_t)(kv * dh + (t >> 3)) * MTOK + b * Tlen + (t & 7) * 8;

    for (int side = 0; side < 2; ++side) {
        int qt = side ? p : (31 - p);
        int qbase = qt * QB;
        int qfrag = qbase + wave * 16;
        short8 qf[4];
        const ushort_t* Qrow = Q + ((size_t)(b * Tlen) + qfrag + l16) * D + h * dh;
#pragma unroll
        for (int kk = 0; kk < 4; ++kk) qf[kk] = *(const short8*)(Qrow + kk * 32 + l4 * 8);
        floatx4 o_acc[8] = {};
        float m_r[4], l_r[4];
#pragma unroll
        for (int r = 0; r < 4; ++r) { m_r[r] = -INFINITY; l_r[r] = 0.f; }
        int nst = qt + 1;
        uint4 kreg[4], vreg[4];
#pragma unroll
        for (int p4 = 0; p4 < 4; ++p4) {
            kreg[p4] = *(const uint4*)(Kg + (size_t)(p4 * 16) * KVD);
            vreg[p4] = *(const uint4*)(Vg + (size_t)(p4 * 32) * MTOK);
        }
        for (int st = 0; st < nst; ++st) {
            __syncthreads();
#pragma unroll
            for (int p4 = 0; p4 < 4; ++p4) {
                *(uint4*)(&Ks[(t >> 4) + p4 * 16][(t & 15) * 8]) = kreg[p4];
                *(uint4*)(&Vt[(t >> 3) + p4 * 32][(t & 7) * 8]) = vreg[p4];
            }
            __syncthreads();
            if (st + 1 < nst) {
                size_t off = (size_t)(st + 1) * SB;
#pragma unroll
                for (int p4 = 0; p4 < 4; ++p4) {
                    kreg[p4] = *(const uint4*)(Kg + (off + p4 * 16) * KVD);
                    vreg[p4] = *(const uint4*)(Vg + (size_t)(p4 * 32) * MTOK + off);
                }
            }
            int s0 = st * SB;
            // QK^T
            floatx4 sa[4] = {};
            __builtin_amdgcn_s_setprio(1);
#pragma unroll
            for (int ss = 0; ss < 4; ++ss)
#pragma unroll
                for (int kk = 0; kk < 4; ++kk) {
                    short8 kf = *(const short8*)(&Ks[ss * 16 + l16][kk * 32 + l4 * 8]);
                    sa[ss] = __builtin_amdgcn_mfma_f32_16x16x32_bf16(qf[kk], kf, sa[ss], 0, 0, 0);
                }
            __builtin_amdgcn_s_setprio(0);
            // softmax (online, T13 defer-max THR=8)
            float sv[4][4], pmax[4];
#pragma unroll
            for (int r = 0; r < 4; ++r) pmax[r] = -INFINITY;
#pragma unroll
            for (int ss = 0; ss < 4; ++ss) {
                int scol = s0 + ss * 16 + l16;
#pragma unroll
                for (int r = 0; r < 4; ++r) {
                    int qrow = qfrag + l4 * 4 + r;
                    float v = sa[ss][r] * scale;
                    if (scol > qrow) v = -INFINITY;
                    sv[ss][r] = v;
                    pmax[r] = fmaxf(pmax[r], v);
                }
            }
#pragma unroll
            for (int m = 1; m < 16; m <<= 1)
#pragma unroll
                for (int r = 0; r < 4; ++r) pmax[r] = fmaxf(pmax[r], __shfl_xor(pmax[r], m));
            int cflag = 1;
#pragma unroll
            for (int r = 0; r < 4; ++r) cflag &= (pmax[r] <= m_r[r] + 8.f) ? 1 : 0;
            bool skip = __all(cflag);
            float mn[4], rsum[4];
#pragma unroll
            for (int r = 0; r < 4; ++r) {
                mn[r] = skip ? m_r[r] : fmaxf(m_r[r], pmax[r]);
                rsum[r] = 0.f;
            }
#pragma unroll
            for (int ss = 0; ss < 4; ++ss)
#pragma unroll
                for (int r = 0; r < 4; ++r) {
                    float pv = __expf(sv[ss][r] - mn[r]);
                    sv[ss][r] = pv;
                    rsum[r] += pv;
                }
#pragma unroll
            for (int m = 1; m < 16; m <<= 1)
#pragma unroll
                for (int r = 0; r < 4; ++r) rsum[r] += __shfl_xor(rsum[r], m);
            if (skip) {
#pragma unroll
                for (int r = 0; r < 4; ++r) l_r[r] += rsum[r];
            } else {
#pragma unroll
                for (int r = 0; r < 4; ++r) {
                    float esc = __expf(m_r[r] - mn[r]);
                    l_r[r] = l_r[r] * esc + rsum[r];
                    m_r[r] = mn[r];
#pragma unroll
                    for (int c = 0; c < 8; ++c) o_acc[c][r] *= esc;
                }
            }
#pragma unroll
            for (int ss = 0; ss < 4; ++ss)
#pragma unroll
                for (int r = 0; r < 4; ++r)
                    Ps[wave][l4 * 4 + r][ss * 16 + l16] = f2b(sv[ss][r]);
            short8 pa[2];
#pragma unroll
            for (int kk = 0; kk < 2; ++kk)
                pa[kk] = *(const short8*)(&Ps[wave][l16][kk * 32 + l4 * 8]);
            __builtin_amdgcn_s_setprio(1);
#pragma unroll
            for (int c = 0; c < 8; ++c)
#pragma unroll
                for (int kk = 0; kk < 2; ++kk) {
                    short8 vf = *(const short8*)(&Vt[c * 16 + l16][kk * 32 + l4 * 8]);
                    o_acc[c] = __builtin_amdgcn_mfma_f32_16x16x32_bf16(pa[kk], vf, o_acc[c], 0, 0, 0);
                }
            __builtin_amdgcn_s_setprio(0);
        }
#pragma unroll
        for (int c = 0; c < 8; ++c)
#pragma unroll
            for (int r = 0; r < 4; ++r) {
                int qrow = qfrag + l4 * 4 + r;
                int col = h * dh + c * 16 + l16;
                O[((size_t)(b * Tlen) + qrow) * D + col] = f2b(o_acc[c][r] / l_r[r]);
            }
    }
}

extern "C" void kernel_launch(void* const* d_in, const int* in_sizes, int n_in,
                              void* d_out, int out_size, void* d_ws, size_t ws_size,
                              hipStream_t stream) {
    const float* x   = (const float*)d_in[0];
    const float* n1w = (const float*)d_in[1];
    const float* n2w = (const float*)d_in[2];
    const float* Wq  = (const float*)d_in[3];
    const float* Wk  = (const float*)d_in[4];
    const float* Wv  = (const float*)d_in[5];
    const float* Wo  = (const float*)d_in[6];
    const float* Wc  = (const float*)d_in[7];
    const float* W1  = (const float*)d_in[8];
    const float* W2  = (const float*)d_in[9];
    const float* W3  = (const float*)d_in[10];
    float* out = (float*)d_out;

    const int B = 2, T = 2048, D = 2048, F = 8192, KVD = 512;
    const int M = B * T;  // 4096
    const size_t XD   = (size_t)M * D * 2;
    const size_t XDF  = (size_t)M * D * 4;
    const size_t KVSZ = (size_t)M * KVD * 2;
    const size_t MF   = (size_t)M * F * 2;
    const size_t WDD  = (size_t)D * D * 2;
    const size_t WDK  = (size_t)D * KVD * 2;
    const size_t WDF  = (size_t)D * F * 2;

    char* w = (char*)d_ws;
    ushort_t* xn    = (ushort_t*)(w);
    ushort_t* qtmp  = (ushort_t*)(w + XD);
    ushort_t* qfin  = (ushort_t*)(w + 2 * XD);
    float*    x2f   = (float*)   (w + 3 * XD);
    ushort_t* kbuf  = (ushort_t*)(w + 3 * XD + XDF);
    ushort_t* vbufT = (ushort_t*)(w + 3 * XD + XDF + KVSZ);
    ushort_t* h1    = (ushort_t*)(w + 3 * XD + XDF + 2 * KVSZ);
    char* wt = w + 3 * XD + XDF + 2 * KVSZ + MF;
    ushort_t* WqT = (ushort_t*)(wt);
    ushort_t* WcT = (ushort_t*)(wt + WDD);
    ushort_t* WoT = (ushort_t*)(wt + 2 * WDD);
    ushort_t* WkT = (ushort_t*)(wt + 3 * WDD);
    ushort_t* WvT = (ushort_t*)(wt + 3 * WDD + WDK);
    ushort_t* W1T = (ushort_t*)(wt + 3 * WDD + 2 * WDK);
    ushort_t* W3T = (ushort_t*)(wt + 3 * WDD + 2 * WDK + WDF);
    ushort_t* W2T = (ushort_t*)(wt + 3 * WDD + 2 * WDK + 2 * WDF);

    dim3 blk(256);

    transpose_w<<<dim3(D / 64, D / 64), blk, 0, stream>>>(Wq, WqT, D, D);
    transpose_w<<<dim3(D / 64, D / 64), blk, 0, stream>>>(Wc, WcT, D, D);
    transpose_w<<<dim3(D / 64, D / 64), blk, 0, stream>>>(Wo, WoT, D, D);
    transpose_w<<<dim3(D / 64, KVD / 64), blk, 0, stream>>>(Wk, WkT, D, KVD);
    transpose_w<<<dim3(D / 64, KVD / 64), blk, 0, stream>>>(Wv, WvT, D, KVD);
    transpose_w<<<dim3(D / 64, F / 64), blk, 0, stream>>>(W1, W1T, D, F);
    transpose_w<<<dim3(D / 64, F / 64), blk, 0, stream>>>(W3, W3T, D, F);
    transpose_w<<<dim3(F / 64, D / 64), blk, 0, stream>>>(W2, W2T, F, D);

    rmsnorm_kernel<<<M, blk, 0, stream>>>(x, n1w, xn, D);
    gemm_bt<0, false, false><<<dim3(M / BM, D / BN), blk, 0, stream>>>(xn, WqT, nullptr, qtmp, M, D, D);
    gemm_bt<1, false, false><<<dim3(M / BM, D / BN), blk, 0, stream>>>(qtmp, WcT, qtmp, qfin, M, D, D);
    gemm_bt<0, false, false><<<dim3(M / BM, KVD / BN), blk, 0, stream>>>(xn, WkT, nullptr, kbuf, M, KVD, D);
    gemm_bt<0, false, false, true><<<dim3(M / BM, KVD / BN), blk, 0, stream>>>(xn, WvT, nullptr, vbufT, M, KVD, D);
    // causal-balanced attention: 16 pairs of q-tiles
    attn_kernel<<<dim3(16, 16, B), blk, 0, stream>>>(qfin, kbuf, vbufT, qtmp, T);
    gemm_bt<1, true, true><<<dim3(M / BM, D / BN), blk, 0, stream>>>(qtmp, WoT, x, x2f, M, D, D);
    rmsnorm_kernel<<<M, blk, 0, stream>>>(x2f, n2w, xn, D);
    // MLP: h1 = xn2 @ W1 ; h1 = silu(h1) * (xn2 @ W3)   [256^2 8-phase, XOR-8 swizzle]
    gemm8<0><<<dim3((M / 256) * (F / 256)), dim3(512), 0, stream>>>(xn, W1T, nullptr, h1, M, F, D);
    gemm8<2><<<dim3((M / 256) * (F / 256)), dim3(512), 0, stream>>>(xn, W3T, h1, h1, M, F, D);
    gemm_bt<1, true, true><<<dim3(M / BM, D / BN), blk, 0, stream>>>(h1, W2T, x2f, out, M, D, F);
}

// Round 8
// 876.143 us; speedup vs baseline: 1.2890x; 1.2022x over previous
//
#include <hip/hip_runtime.h>
#include <hip/hip_bf16.h>

typedef __attribute__((ext_vector_type(8))) short short8;
typedef __attribute__((ext_vector_type(4))) float floatx4;
typedef unsigned short ushort_t;

__device__ inline float b2f(ushort_t s) {
    return __uint_as_float(((unsigned int)s) << 16);
}
__device__ inline ushort_t f2b(float f) {
    unsigned int u = __float_as_uint(f);
    unsigned int r = 0x7fff + ((u >> 16) & 1);
    return (ushort_t)((u + r) >> 16);
}
__device__ inline void load8(const float* p, float* f) {
    float4 a = *(const float4*)p;
    float4 b = *(const float4*)(p + 4);
    f[0] = a.x; f[1] = a.y; f[2] = a.z; f[3] = a.w;
    f[4] = b.x; f[5] = b.y; f[6] = b.z; f[7] = b.w;
}
__device__ inline void gload16(const ushort_t* g, ushort_t* l) {
    __builtin_amdgcn_global_load_lds(
        (const __attribute__((address_space(1))) unsigned int*)g,
        (__attribute__((address_space(3))) unsigned int*)l, 16, 0, 0);
}

// ---------- weight pre-pass: fp32 [K,N] -> bf16 [N,K] ----------
__global__ __launch_bounds__(256) void transpose_w(const float* __restrict__ src,
                                                   ushort_t* __restrict__ dst,
                                                   int K, int N) {
    __shared__ ushort_t tile[64][65];
    int kb = blockIdx.x * 64, nb = blockIdx.y * 64;
    int t = threadIdx.x;
#pragma unroll
    for (int i = 0; i < 4; ++i) {
        int r = (t >> 4) + i * 16;
        int c = (t & 15) * 4;
        float4 v = *(const float4*)(src + (size_t)(kb + r) * N + nb + c);
        tile[c + 0][r] = f2b(v.x);
        tile[c + 1][r] = f2b(v.y);
        tile[c + 2][r] = f2b(v.z);
        tile[c + 3][r] = f2b(v.w);
    }
    __syncthreads();
#pragma unroll
    for (int i = 0; i < 2; ++i) {
        int s = t + i * 256;
        int n = s >> 3, kc = (s & 7) * 8;
        ushort_t o[8];
#pragma unroll
        for (int j = 0; j < 8; ++j) o[j] = tile[n][kc + j];
        *(uint4*)(dst + (size_t)(nb + n) * K + kb + kc) = *(const uint4*)o;
    }
}

// ---------------- RMSNorm: fp32 in -> bf16 out ----------------
__global__ __launch_bounds__(256) void rmsnorm_kernel(const float* __restrict__ x,
                                                      const float* __restrict__ w,
                                                      ushort_t* __restrict__ out, int D) {
    int row = blockIdx.x;
    int t = threadIdx.x;
    const float* xr = x + (size_t)row * D;
    float f[8];
    load8(xr + t * 8, f);
    float ss = 0.f;
#pragma unroll
    for (int i = 0; i < 8; ++i) ss += f[i] * f[i];
#pragma unroll
    for (int m = 1; m < 64; m <<= 1) ss += __shfl_xor(ss, m);
    __shared__ float wsum[4];
    if ((t & 63) == 0) wsum[t >> 6] = ss;
    __syncthreads();
    float tot = wsum[0] + wsum[1] + wsum[2] + wsum[3];
    float r = rsqrtf(tot / (float)D + 1e-6f);
    float wf[8];
    load8(w + t * 8, wf);
    ushort_t o[8];
#pragma unroll
    for (int i = 0; i < 8; ++i) o[i] = f2b(f[i] * r * wf[i]);
    *(uint4*)(out + (size_t)row * D + t * 8) = *(const uint4*)o;
}

// ---------------- final reduce: out = p0 + p1 + resid  (p bf16, resid/out fp32) ----------------
__global__ __launch_bounds__(256) void reduce_out(const ushort_t* __restrict__ p,
                                                  const float* __restrict__ resid,
                                                  float* __restrict__ out, int n) {
    int stride = gridDim.x * 256;
    for (int i = blockIdx.x * 256 + threadIdx.x; i * 8 < n; i += stride) {
        int i8 = i * 8;
        uint4 a = *(const uint4*)(p + i8);
        uint4 b = *(const uint4*)(p + n + i8);
        const ushort_t* ae = (const ushort_t*)&a;
        const ushort_t* be = (const ushort_t*)&b;
        float rr[8];
        load8(resid + i8, rr);
        float o[8];
#pragma unroll
        for (int j = 0; j < 8; ++j) o[j] = b2f(ae[j]) + b2f(be[j]) + rr[j];
        *(float4*)(out + i8) = make_float4(o[0], o[1], o[2], o[3]);
        *(float4*)(out + i8 + 4) = make_float4(o[4], o[5], o[6], o[7]);
    }
}

// ---------------- 256x256 8-phase GEMM (BK=64, 8 waves, XOR-8 swizzle) ----------------
// MODE 0: C=AB (bf16) ; 1: C=AB+aux(bf16) ; 2: C=silu(aux)*AB (bf16)
// MODE 3: bf16 K-split partial -> Cv + blockIdx.y*M*N
// MODE 5: fp32 C = AB + aux2(fp32)
// MODE 6: QKV split epilogue: cols [0,2048)->Cv row-major, [2048,2560)->C2v row-major,
//         [2560,3072)->C3v transposed [d][tok] (tok stride 4096)
__device__ inline void vm6() { asm volatile("s_waitcnt vmcnt(6)" ::: "memory"); }

template <int MODE>
__global__ __launch_bounds__(512, 2) void gemm8(const ushort_t* __restrict__ A,
                                                const ushort_t* __restrict__ Bt,
                                                const ushort_t* __restrict__ aux,
                                                const float* __restrict__ aux2,
                                                void* __restrict__ Cv,
                                                void* __restrict__ C2v,
                                                void* __restrict__ C3v,
                                                int M, int N, int Ksub, int lda) {
    __shared__ __align__(16) ushort_t Lds[2 * 32768];
    const int tid = threadIdx.x;
    const int wv = tid >> 6, lane = tid & 63;
    const int l16 = lane & 15, l4 = lane >> 4;
    const int wr = wv >> 2, wc = wv & 3;
    // XCD-aware block swizzle (gridDim.x % 8 == 0)
    int nwg = gridDim.x;
    int per = nwg >> 3;
    int wg = (blockIdx.x & 7) * per + (blockIdx.x >> 3);
    int mtiles = M >> 8;
    int bx = wg & (mtiles - 1);
    int by = wg / mtiles;
    int bm = bx << 8, bn = by << 8;
    int koff = blockIdx.y * Ksub;

    const int sr = tid >> 3;
    const int scol = (((tid & 7) ^ (sr & 7)) << 3);
    const ushort_t* gA = A + (size_t)(bm + sr) * lda + scol + koff;
    const ushort_t* gB = Bt + (size_t)(bn + sr) * lda + scol + koff;
    ushort_t* ldsw = Lds + wv * 512;

    const int ktiles = Ksub >> 6;
    const int niter = ktiles >> 1;
    const int km = ktiles - 1;

#define STG_A(slot, j, kt) gload16(gA + (size_t)((j) * 64) * lda + ((kt) << 6), ldsw + (slot) * 32768 + (j) * 4096)
#define STG_B(slot, j, kt) gload16(gB + (size_t)((j) * 64) * lda + ((kt) << 6), ldsw + (slot) * 32768 + 16384 + (j) * 4096)

    STG_A(0, 0, 0); STG_A(0, 2, 0); STG_A(0, 1, 0); STG_A(0, 3, 0);
    STG_B(0, 0, 0); STG_B(0, 1, 0); STG_B(0, 2, 0); STG_B(0, 3, 0);
    STG_A(1, 0, 1); STG_A(1, 2, 1);
    STG_B(1, 0, 1); STG_B(1, 1, 1); STG_B(1, 2, 1); STG_B(1, 3, 1);
    vm6();
    asm volatile("" ::: "memory");
    __builtin_amdgcn_s_barrier();

    const int lx = l4 ^ (l16 & 7);
    floatx4 acc[8][4] = {};
    short8 aR[4][2], bR[4][2];

#define DSA(slot, mh) { _Pragma("unroll") for (int m = 0; m < 4; ++m) { \
    _Pragma("unroll") for (int kk = 0; kk < 2; ++kk) \
      aR[m][kk] = *(const short8*)(Lds + (slot) * 32768 + \
          (wr * 128 + (mh) * 64 + m * 16 + l16) * 64 + ((lx ^ (kk << 2)) << 3)); } }
#define DSB(slot, nh) { _Pragma("unroll") for (int n = 0; n < 2; ++n) { \
    _Pragma("unroll") for (int kk = 0; kk < 2; ++kk) \
      bR[(nh) * 2 + n][kk] = *(const short8*)(Lds + (slot) * 32768 + 16384 + \
          (wc * 64 + ((nh) * 2 + n) * 16 + l16) * 64 + ((lx ^ (kk << 2)) << 3)); } }
#define QUAD(mh, nlo) { _Pragma("unroll") for (int m = 0; m < 4; ++m) \
    _Pragma("unroll") for (int n = 0; n < 2; ++n) \
    _Pragma("unroll") for (int kk = 0; kk < 2; ++kk) \
      acc[(mh) * 4 + m][(nlo) + n] = __builtin_amdgcn_mfma_f32_16x16x32_bf16( \
          aR[m][kk], bR[(nlo) + n][kk], acc[(mh) * 4 + m][(nlo) + n], 0, 0, 0); }
#define PHASE(DS, ST, MH, NLO, VM) { \
    DS; ST; \
    asm volatile("" ::: "memory"); \
    __builtin_amdgcn_s_barrier(); \
    asm volatile("s_waitcnt lgkmcnt(0)" ::: "memory"); \
    __builtin_amdgcn_sched_barrier(0); \
    __builtin_amdgcn_s_setprio(1); \
    QUAD(MH, NLO); \
    __builtin_amdgcn_s_setprio(0); \
    VM; \
    asm volatile("" ::: "memory"); \
    __builtin_amdgcn_s_barrier(); }

    for (int it = 0; it < niter; ++it) {
        int t1 = 2 * it + 1;
        int t2 = (2 * it + 2) & km;
        int t3 = (2 * it + 3) & km;
        PHASE({ DSA(0, 0); DSB(0, 0); }, { STG_A(1, 1, t1); STG_A(1, 3, t1); }, 0, 0, );
        PHASE({ DSB(0, 1); },            { STG_A(0, 0, t2); STG_A(0, 2, t2); }, 0, 2, );
        PHASE({ DSA(0, 1); },            { STG_B(0, 0, t2); STG_B(0, 1, t2); }, 1, 2, );
        PHASE({ },                       { STG_B(0, 2, t2); STG_B(0, 3, t2); }, 1, 0, vm6(); );
        PHASE({ DSA(1, 0); DSB(1, 0); }, { STG_A(0, 1, t2); STG_A(0, 3, t2); }, 0, 0, );
        PHASE({ DSB(1, 1); },            { STG_A(1, 0, t3); STG_A(1, 2, t3); }, 0, 2, );
        PHASE({ DSA(1, 1); },            { STG_B(1, 0, t3); STG_B(1, 1, t3); }, 1, 2, );
        PHASE({ },                       { STG_B(1, 2, t3); STG_B(1, 3, t3); }, 1, 0, vm6(); );
    }

    // epilogue
#pragma unroll
    for (int mi = 0; mi < 8; ++mi)
#pragma unroll
        for (int ni = 0; ni < 4; ++ni)
#pragma unroll
            for (int r = 0; r < 4; ++r) {
                int row = bm + wr * 128 + mi * 16 + l4 * 4 + r;
                int col = bn + wc * 64 + ni * 16 + l16;
                size_t idx = (size_t)row * N + col;
                float v = acc[mi][ni][r];
                if (MODE == 0) {
                    ((ushort_t*)Cv)[idx] = f2b(v);
                } else if (MODE == 1) {
                    ((ushort_t*)Cv)[idx] = f2b(v + b2f(aux[idx]));
                } else if (MODE == 2) {
                    float h = b2f(aux[idx]);
                    ((ushort_t*)Cv)[idx] = f2b((h / (1.f + __expf(-h))) * v);
                } else if (MODE == 3) {
                    ((ushort_t*)Cv)[(size_t)blockIdx.y * M * N + idx] = f2b(v);
                } else if (MODE == 5) {
                    ((float*)Cv)[idx] = v + aux2[idx];
                } else if (MODE == 6) {
                    if (bn < 2048) {
                        ((ushort_t*)Cv)[(size_t)row * 2048 + col] = f2b(v);
                    } else if (bn < 2560) {
                        ((ushort_t*)C2v)[(size_t)row * 512 + (col - 2048)] = f2b(v);
                    } else {
                        ((ushort_t*)C3v)[(size_t)(col - 2560) * 4096 + row] = f2b(v);
                    }
                }
            }
#undef STG_A
#undef STG_B
#undef DSA
#undef DSB
#undef QUAD
#undef PHASE
}

// ---------------- Flash attention (causal, GQA), QB=64, SB=64, causal-balanced pairs ----------------
#define QB 64
#define SB 64

__global__ __launch_bounds__(256, 2) void attn_kernel(const ushort_t* __restrict__ Q,
                                                      const ushort_t* __restrict__ Kb,
                                                      const ushort_t* __restrict__ VbT,
                                                      ushort_t* __restrict__ O, int Tlen) {
    const int D = 2048, KVD = 512, dh = 128;
    const int MTOK = 4096;
    int p = blockIdx.x, h = blockIdx.y, b = blockIdx.z;
    int kv = h >> 2;
    int t = threadIdx.x, wave = t >> 6, lane = t & 63;
    int l16 = lane & 15, l4 = lane >> 4;
    __shared__ __align__(16) ushort_t Ks[SB][dh + 8];
    __shared__ __align__(16) ushort_t Vt[dh][SB + 8];
    __shared__ __align__(16) ushort_t Ps[4][16][SB + 8];
    const float scale = 0.08838834764831845f;
    const ushort_t* Kg = Kb + ((size_t)(b * Tlen) + (t >> 4)) * KVD + kv * dh + (t & 15) * 8;
    const ushort_t* Vg = VbT + (size_t)(kv * dh + (t >> 3)) * MTOK + b * Tlen + (t & 7) * 8;

    for (int side = 0; side < 2; ++side) {
        int qt = side ? p : (31 - p);
        int qbase = qt * QB;
        int qfrag = qbase + wave * 16;
        short8 qf[4];
        const ushort_t* Qrow = Q + ((size_t)(b * Tlen) + qfrag + l16) * D + h * dh;
#pragma unroll
        for (int kk = 0; kk < 4; ++kk) qf[kk] = *(const short8*)(Qrow + kk * 32 + l4 * 8);
        floatx4 o_acc[8] = {};
        float m_r[4], l_r[4];
#pragma unroll
        for (int r = 0; r < 4; ++r) { m_r[r] = -INFINITY; l_r[r] = 0.f; }
        int nst = qt + 1;
        uint4 kreg[4], vreg[4];
#pragma unroll
        for (int p4 = 0; p4 < 4; ++p4) {
            kreg[p4] = *(const uint4*)(Kg + (size_t)(p4 * 16) * KVD);
            vreg[p4] = *(const uint4*)(Vg + (size_t)(p4 * 32) * MTOK);
        }
        for (int st = 0; st < nst; ++st) {
            __syncthreads();
#pragma unroll
            for (int p4 = 0; p4 < 4; ++p4) {
                *(uint4*)(&Ks[(t >> 4) + p4 * 16][(t & 15) * 8]) = kreg[p4];
                *(uint4*)(&Vt[(t >> 3) + p4 * 32][(t & 7) * 8]) = vreg[p4];
            }
            __syncthreads();
            if (st + 1 < nst) {
                size_t off = (size_t)(st + 1) * SB;
#pragma unroll
                for (int p4 = 0; p4 < 4; ++p4) {
                    kreg[p4] = *(const uint4*)(Kg + (off + p4 * 16) * KVD);
                    vreg[p4] = *(const uint4*)(Vg + (size_t)(p4 * 32) * MTOK + off);
                }
            }
            int s0 = st * SB;
            floatx4 sa[4] = {};
            __builtin_amdgcn_s_setprio(1);
#pragma unroll
            for (int ss = 0; ss < 4; ++ss)
#pragma unroll
                for (int kk = 0; kk < 4; ++kk) {
                    short8 kf = *(const short8*)(&Ks[ss * 16 + l16][kk * 32 + l4 * 8]);
                    sa[ss] = __builtin_amdgcn_mfma_f32_16x16x32_bf16(qf[kk], kf, sa[ss], 0, 0, 0);
                }
            __builtin_amdgcn_s_setprio(0);
            float sv[4][4], pmax[4];
#pragma unroll
            for (int r = 0; r < 4; ++r) pmax[r] = -INFINITY;
#pragma unroll
            for (int ss = 0; ss < 4; ++ss) {
                int scol = s0 + ss * 16 + l16;
#pragma unroll
                for (int r = 0; r < 4; ++r) {
                    int qrow = qfrag + l4 * 4 + r;
                    float v = sa[ss][r] * scale;
                    if (scol > qrow) v = -INFINITY;
                    sv[ss][r] = v;
                    pmax[r] = fmaxf(pmax[r], v);
                }
            }
#pragma unroll
            for (int m = 1; m < 16; m <<= 1)
#pragma unroll
                for (int r = 0; r < 4; ++r) pmax[r] = fmaxf(pmax[r], __shfl_xor(pmax[r], m));
            int cflag = 1;
#pragma unroll
            for (int r = 0; r < 4; ++r) cflag &= (pmax[r] <= m_r[r] + 8.f) ? 1 : 0;
            bool skip = __all(cflag);
            float mn[4], rsum[4];
#pragma unroll
            for (int r = 0; r < 4; ++r) {
                mn[r] = skip ? m_r[r] : fmaxf(m_r[r], pmax[r]);
                rsum[r] = 0.f;
            }
#pragma unroll
            for (int ss = 0; ss < 4; ++ss)
#pragma unroll
                for (int r = 0; r < 4; ++r) {
                    float pv = __expf(sv[ss][r] - mn[r]);
                    sv[ss][r] = pv;
                    rsum[r] += pv;
                }
#pragma unroll
            for (int m = 1; m < 16; m <<= 1)
#pragma unroll
                for (int r = 0; r < 4; ++r) rsum[r] += __shfl_xor(rsum[r], m);
            if (skip) {
#pragma unroll
                for (int r = 0; r < 4; ++r) l_r[r] += rsum[r];
            } else {
#pragma unroll
                for (int r = 0; r < 4; ++r) {
                    float esc = __expf(m_r[r] - mn[r]);
                    l_r[r] = l_r[r] * esc + rsum[r];
                    m_r[r] = mn[r];
#pragma unroll
                    for (int c = 0; c < 8; ++c) o_acc[c][r] *= esc;
                }
            }
#pragma unroll
            for (int ss = 0; ss < 4; ++ss)
#pragma unroll
                for (int r = 0; r < 4; ++r)
                    Ps[wave][l4 * 4 + r][ss * 16 + l16] = f2b(sv[ss][r]);
            short8 pa[2];
#pragma unroll
            for (int kk = 0; kk < 2; ++kk)
                pa[kk] = *(const short8*)(&Ps[wave][l16][kk * 32 + l4 * 8]);
            __builtin_amdgcn_s_setprio(1);
#pragma unroll
            for (int c = 0; c < 8; ++c)
#pragma unroll
                for (int kk = 0; kk < 2; ++kk) {
                    short8 vf = *(const short8*)(&Vt[c * 16 + l16][kk * 32 + l4 * 8]);
                    o_acc[c] = __builtin_amdgcn_mfma_f32_16x16x32_bf16(pa[kk], vf, o_acc[c], 0, 0, 0);
                }
            __builtin_amdgcn_s_setprio(0);
        }
#pragma unroll
        for (int c = 0; c < 8; ++c)
#pragma unroll
            for (int r = 0; r < 4; ++r) {
                int qrow = qfrag + l4 * 4 + r;
                int col = h * dh + c * 16 + l16;
                O[((size_t)(b * Tlen) + qrow) * D + col] = f2b(o_acc[c][r] / l_r[r]);
            }
    }
}

extern "C" void kernel_launch(void* const* d_in, const int* in_sizes, int n_in,
                              void* d_out, int out_size, void* d_ws, size_t ws_size,
                              hipStream_t stream) {
    const float* x   = (const float*)d_in[0];
    const float* n1w = (const float*)d_in[1];
    const float* n2w = (const float*)d_in[2];
    const float* Wq  = (const float*)d_in[3];
    const float* Wk  = (const float*)d_in[4];
    const float* Wv  = (const float*)d_in[5];
    const float* Wo  = (const float*)d_in[6];
    const float* Wc  = (const float*)d_in[7];
    const float* W1  = (const float*)d_in[8];
    const float* W2  = (const float*)d_in[9];
    const float* W3  = (const float*)d_in[10];
    float* out = (float*)d_out;

    const int B = 2, T = 2048, D = 2048, F = 8192, KVD = 512;
    const int M = B * T;  // 4096
    const size_t XD   = (size_t)M * D * 2;     // 16.78 MB
    const size_t XDF  = (size_t)M * D * 4;
    const size_t KVSZ = (size_t)M * KVD * 2;
    const size_t MF   = (size_t)M * F * 2;
    const size_t WDD  = (size_t)D * D * 2;
    const size_t WQKV = (size_t)(D + 2 * KVD) * D * 2;  // merged [3072,2048]
    const size_t WDF  = (size_t)D * F * 2;

    char* w = (char*)d_ws;
    ushort_t* xn    = (ushort_t*)(w);            // later: p0 (W2 partial 0)
    ushort_t* qtmp  = (ushort_t*)(w + XD);       // later: p1 (W2 partial 1); p0/p1 contiguous
    ushort_t* qfin  = (ushort_t*)(w + 2 * XD);
    float*    x2f   = (float*)   (w + 3 * XD);
    ushort_t* kbuf  = (ushort_t*)(w + 3 * XD + XDF);
    ushort_t* vbufT = (ushort_t*)(w + 3 * XD + XDF + KVSZ);
    ushort_t* h1    = (ushort_t*)(w + 3 * XD + XDF + 2 * KVSZ);
    char* wt = w + 3 * XD + XDF + 2 * KVSZ + MF;
    ushort_t* WqkvT = (ushort_t*)(wt);                       // [3072, 2048] = WqT | WkT | WvT
    ushort_t* WcT   = (ushort_t*)(wt + WQKV);
    ushort_t* WoT   = (ushort_t*)(wt + WQKV + WDD);
    ushort_t* W1T   = (ushort_t*)(wt + WQKV + 2 * WDD);
    ushort_t* W3T   = (ushort_t*)(wt + WQKV + 2 * WDD + WDF);
    ushort_t* W2T   = (ushort_t*)(wt + WQKV + 2 * WDD + 2 * WDF);

    dim3 blk(256);
    dim3 blk8(512);

    transpose_w<<<dim3(D / 64, D / 64), blk, 0, stream>>>(Wq, WqkvT, D, D);
    transpose_w<<<dim3(D / 64, KVD / 64), blk, 0, stream>>>(Wk, WqkvT + (size_t)2048 * D, D, KVD);
    transpose_w<<<dim3(D / 64, KVD / 64), blk, 0, stream>>>(Wv, WqkvT + (size_t)2560 * D, D, KVD);
    transpose_w<<<dim3(D / 64, D / 64), blk, 0, stream>>>(Wc, WcT, D, D);
    transpose_w<<<dim3(D / 64, D / 64), blk, 0, stream>>>(Wo, WoT, D, D);
    transpose_w<<<dim3(D / 64, F / 64), blk, 0, stream>>>(W1, W1T, D, F);
    transpose_w<<<dim3(D / 64, F / 64), blk, 0, stream>>>(W3, W3T, D, F);
    transpose_w<<<dim3(F / 64, D / 64), blk, 0, stream>>>(W2, W2T, F, D);

    // xn = rmsnorm(x, n1)
    rmsnorm_kernel<<<M, blk, 0, stream>>>(x, n1w, xn, D);
    // merged QKV: qtmp = xn@Wq ; kbuf = xn@Wk ; vbufT = (xn@Wv)^T
    gemm8<6><<<dim3((M / 256) * (3072 / 256)), blk8, 0, stream>>>(
        xn, WqkvT, nullptr, nullptr, qtmp, kbuf, vbufT, M, 3072, D, D);
    // qfin = qtmp @ Wc + qtmp
    gemm8<1><<<dim3((M / 256) * (D / 256)), blk8, 0, stream>>>(
        qtmp, WcT, qtmp, nullptr, qfin, nullptr, nullptr, M, D, D, D);
    // attention -> qtmp
    attn_kernel<<<dim3(16, 16, B), blk, 0, stream>>>(qfin, kbuf, vbufT, qtmp, T);
    // x2 = att @ Wo + x  (fp32)
    gemm8<5><<<dim3((M / 256) * (D / 256)), blk8, 0, stream>>>(
        qtmp, WoT, nullptr, x, x2f, nullptr, nullptr, M, D, D, D);
    // xn2 = rmsnorm(x2, n2) -> xn slot
    rmsnorm_kernel<<<M, blk, 0, stream>>>(x2f, n2w, xn, D);
    // h1 = xn2 @ W1 ; h1 = silu(h1) * (xn2 @ W3)
    gemm8<0><<<dim3((M / 256) * (F / 256)), blk8, 0, stream>>>(
        xn, W1T, nullptr, nullptr, h1, nullptr, nullptr, M, F, D, D);
    gemm8<2><<<dim3((M / 256) * (F / 256)), blk8, 0, stream>>>(
        xn, W3T, h1, nullptr, h1, nullptr, nullptr, M, F, D, D);
    // W2 split-K x2 (one launch, grid.y = K-half) -> bf16 partials in xn/qtmp slots
    gemm8<3><<<dim3((M / 256) * (D / 256), 2), blk8, 0, stream>>>(
        h1, W2T, nullptr, nullptr, xn, nullptr, nullptr, M, D, F / 2, F);
    // out = p0 + p1 + x2
    reduce_out<<<1024, blk, 0, stream>>>(xn, x2f, out, M * D);
}

// Round 9
// 837.170 us; speedup vs baseline: 1.3490x; 1.0466x over previous
//
#include <hip/hip_runtime.h>
#include <hip/hip_bf16.h>

typedef __attribute__((ext_vector_type(8))) short short8;
typedef __attribute__((ext_vector_type(4))) float floatx4;
typedef unsigned short ushort_t;

__device__ inline float b2f(ushort_t s) {
    return __uint_as_float(((unsigned int)s) << 16);
}
__device__ inline ushort_t f2b(float f) {
    unsigned int u = __float_as_uint(f);
    unsigned int r = 0x7fff + ((u >> 16) & 1);
    return (ushort_t)((u + r) >> 16);
}
__device__ inline void load8(const float* p, float* f) {
    float4 a = *(const float4*)p;
    float4 b = *(const float4*)(p + 4);
    f[0] = a.x; f[1] = a.y; f[2] = a.z; f[3] = a.w;
    f[4] = b.x; f[5] = b.y; f[6] = b.z; f[7] = b.w;
}
__device__ inline void gload16(const ushort_t* g, ushort_t* l) {
    __builtin_amdgcn_global_load_lds(
        (const __attribute__((address_space(1))) unsigned int*)g,
        (__attribute__((address_space(3))) unsigned int*)l, 16, 0, 0);
}

// ---------- weight pre-pass: fp32 [K,N] -> bf16 [N,K] ----------
__global__ __launch_bounds__(256) void transpose_w(const float* __restrict__ src,
                                                   ushort_t* __restrict__ dst,
                                                   int K, int N) {
    __shared__ ushort_t tile[64][65];
    int kb = blockIdx.x * 64, nb = blockIdx.y * 64;
    int t = threadIdx.x;
#pragma unroll
    for (int i = 0; i < 4; ++i) {
        int r = (t >> 4) + i * 16;
        int c = (t & 15) * 4;
        float4 v = *(const float4*)(src + (size_t)(kb + r) * N + nb + c);
        tile[c + 0][r] = f2b(v.x);
        tile[c + 1][r] = f2b(v.y);
        tile[c + 2][r] = f2b(v.z);
        tile[c + 3][r] = f2b(v.w);
    }
    __syncthreads();
#pragma unroll
    for (int i = 0; i < 2; ++i) {
        int s = t + i * 256;
        int n = s >> 3, kc = (s & 7) * 8;
        ushort_t o[8];
#pragma unroll
        for (int j = 0; j < 8; ++j) o[j] = tile[n][kc + j];
        *(uint4*)(dst + (size_t)(nb + n) * K + kb + kc) = *(const uint4*)o;
    }
}

// ---------------- RMSNorm: fp32 in -> bf16 out ----------------
__global__ __launch_bounds__(256) void rmsnorm_kernel(const float* __restrict__ x,
                                                      const float* __restrict__ w,
                                                      ushort_t* __restrict__ out, int D) {
    int row = blockIdx.x;
    int t = threadIdx.x;
    const float* xr = x + (size_t)row * D;
    float f[8];
    load8(xr + t * 8, f);
    float ss = 0.f;
#pragma unroll
    for (int i = 0; i < 8; ++i) ss += f[i] * f[i];
#pragma unroll
    for (int m = 1; m < 64; m <<= 1) ss += __shfl_xor(ss, m);
    __shared__ float wsum[4];
    if ((t & 63) == 0) wsum[t >> 6] = ss;
    __syncthreads();
    float tot = wsum[0] + wsum[1] + wsum[2] + wsum[3];
    float r = rsqrtf(tot / (float)D + 1e-6f);
    float wf[8];
    load8(w + t * 8, wf);
    ushort_t o[8];
#pragma unroll
    for (int i = 0; i < 8; ++i) o[i] = f2b(f[i] * r * wf[i]);
    *(uint4*)(out + (size_t)row * D + t * 8) = *(const uint4*)o;
}

// ---------------- final reduce: out = p0 + p1 + resid ----------------
__global__ __launch_bounds__(256) void reduce_out(const ushort_t* __restrict__ p,
                                                  const float* __restrict__ resid,
                                                  float* __restrict__ out, int n) {
    int stride = gridDim.x * 256;
    for (int i = blockIdx.x * 256 + threadIdx.x; i * 8 < n; i += stride) {
        int i8 = i * 8;
        uint4 a = *(const uint4*)(p + i8);
        uint4 b = *(const uint4*)(p + n + i8);
        const ushort_t* ae = (const ushort_t*)&a;
        const ushort_t* be = (const ushort_t*)&b;
        float rr[8];
        load8(resid + i8, rr);
        float o[8];
#pragma unroll
        for (int j = 0; j < 8; ++j) o[j] = b2f(ae[j]) + b2f(be[j]) + rr[j];
        *(float4*)(out + i8) = make_float4(o[0], o[1], o[2], o[3]);
        *(float4*)(out + i8 + 4) = make_float4(o[4], o[5], o[6], o[7]);
    }
}

__device__ inline void vm6() { asm volatile("s_waitcnt vmcnt(6)" ::: "memory"); }
__device__ inline void vm4() { asm volatile("s_waitcnt vmcnt(4)" ::: "memory"); }

// ---------------- 256x256 8-phase GEMM (BK=64, 8 waves, XOR-8 swizzle) ----------------
// MODE 0: C=AB bf16 ; 1: +aux bf16 ; 2: silu(aux)*AB ; 3: K-split partial ; 5: fp32 +aux2 ; 6: QKV split
template <int MODE>
__global__ __launch_bounds__(512, 2) void gemm8(const ushort_t* __restrict__ A,
                                                const ushort_t* __restrict__ Bt,
                                                const ushort_t* __restrict__ aux,
                                                const float* __restrict__ aux2,
                                                void* __restrict__ Cv,
                                                void* __restrict__ C2v,
                                                void* __restrict__ C3v,
                                                int M, int N, int Ksub, int lda) {
    __shared__ __align__(16) ushort_t Lds[2 * 32768];
    const int tid = threadIdx.x;
    const int wv = tid >> 6, lane = tid & 63;
    const int l16 = lane & 15, l4 = lane >> 4;
    const int wr = wv >> 2, wc = wv & 3;
    int nwg = gridDim.x;
    int per = nwg >> 3;
    int wg = (blockIdx.x & 7) * per + (blockIdx.x >> 3);
    int mtiles = M >> 8;
    int bx = wg & (mtiles - 1);
    int by = wg / mtiles;
    int bm = bx << 8, bn = by << 8;
    int koff = blockIdx.y * Ksub;

    const int sr = tid >> 3;
    const int scol = (((tid & 7) ^ (sr & 7)) << 3);
    const ushort_t* gA = A + (size_t)(bm + sr) * lda + scol + koff;
    const ushort_t* gB = Bt + (size_t)(bn + sr) * lda + scol + koff;
    ushort_t* ldsw = Lds + wv * 512;

    const int ktiles = Ksub >> 6;
    const int niter = ktiles >> 1;
    const int km = ktiles - 1;

#define STG_A(slot, j, kt) gload16(gA + (size_t)((j) * 64) * lda + ((kt) << 6), ldsw + (slot) * 32768 + (j) * 4096)
#define STG_B(slot, j, kt) gload16(gB + (size_t)((j) * 64) * lda + ((kt) << 6), ldsw + (slot) * 32768 + 16384 + (j) * 4096)

    STG_A(0, 0, 0); STG_A(0, 2, 0); STG_A(0, 1, 0); STG_A(0, 3, 0);
    STG_B(0, 0, 0); STG_B(0, 1, 0); STG_B(0, 2, 0); STG_B(0, 3, 0);
    STG_A(1, 0, 1); STG_A(1, 2, 1);
    STG_B(1, 0, 1); STG_B(1, 1, 1); STG_B(1, 2, 1); STG_B(1, 3, 1);
    vm6();
    asm volatile("" ::: "memory");
    __builtin_amdgcn_s_barrier();

    const int lx = l4 ^ (l16 & 7);
    floatx4 acc[8][4] = {};
    short8 aR[4][2], bR[4][2];

#define DSA(slot, mh) { _Pragma("unroll") for (int m = 0; m < 4; ++m) { \
    _Pragma("unroll") for (int kk = 0; kk < 2; ++kk) \
      aR[m][kk] = *(const short8*)(Lds + (slot) * 32768 + \
          (wr * 128 + (mh) * 64 + m * 16 + l16) * 64 + ((lx ^ (kk << 2)) << 3)); } }
#define DSB(slot, nh) { _Pragma("unroll") for (int n = 0; n < 2; ++n) { \
    _Pragma("unroll") for (int kk = 0; kk < 2; ++kk) \
      bR[(nh) * 2 + n][kk] = *(const short8*)(Lds + (slot) * 32768 + 16384 + \
          (wc * 64 + ((nh) * 2 + n) * 16 + l16) * 64 + ((lx ^ (kk << 2)) << 3)); } }
#define QUAD(mh, nlo) { _Pragma("unroll") for (int m = 0; m < 4; ++m) \
    _Pragma("unroll") for (int n = 0; n < 2; ++n) \
    _Pragma("unroll") for (int kk = 0; kk < 2; ++kk) \
      acc[(mh) * 4 + m][(nlo) + n] = __builtin_amdgcn_mfma_f32_16x16x32_bf16( \
          aR[m][kk], bR[(nlo) + n][kk], acc[(mh) * 4 + m][(nlo) + n], 0, 0, 0); }
#define PHASE(DS, ST, MH, NLO, VM) { \
    DS; ST; \
    asm volatile("" ::: "memory"); \
    __builtin_amdgcn_s_barrier(); \
    asm volatile("s_waitcnt lgkmcnt(0)" ::: "memory"); \
    __builtin_amdgcn_sched_barrier(0); \
    __builtin_amdgcn_s_setprio(1); \
    QUAD(MH, NLO); \
    __builtin_amdgcn_s_setprio(0); \
    VM; \
    asm volatile("" ::: "memory"); \
    __builtin_amdgcn_s_barrier(); }

    for (int it = 0; it < niter; ++it) {
        int t1 = 2 * it + 1;
        int t2 = (2 * it + 2) & km;
        int t3 = (2 * it + 3) & km;
        PHASE({ DSA(0, 0); DSB(0, 0); }, { STG_A(1, 1, t1); STG_A(1, 3, t1); }, 0, 0, );
        PHASE({ DSB(0, 1); },            { STG_A(0, 0, t2); STG_A(0, 2, t2); }, 0, 2, );
        PHASE({ DSA(0, 1); },            { STG_B(0, 0, t2); STG_B(0, 1, t2); }, 1, 2, );
        PHASE({ },                       { STG_B(0, 2, t2); STG_B(0, 3, t2); }, 1, 0, vm6(); );
        PHASE({ DSA(1, 0); DSB(1, 0); }, { STG_A(0, 1, t2); STG_A(0, 3, t2); }, 0, 0, );
        PHASE({ DSB(1, 1); },            { STG_A(1, 0, t3); STG_A(1, 2, t3); }, 0, 2, );
        PHASE({ DSA(1, 1); },            { STG_B(1, 0, t3); STG_B(1, 1, t3); }, 1, 2, );
        PHASE({ },                       { STG_B(1, 2, t3); STG_B(1, 3, t3); }, 1, 0, vm6(); );
    }

#pragma unroll
    for (int mi = 0; mi < 8; ++mi)
#pragma unroll
        for (int ni = 0; ni < 4; ++ni)
#pragma unroll
            for (int r = 0; r < 4; ++r) {
                int row = bm + wr * 128 + mi * 16 + l4 * 4 + r;
                int col = bn + wc * 64 + ni * 16 + l16;
                size_t idx = (size_t)row * N + col;
                float v = acc[mi][ni][r];
                if (MODE == 0) {
                    ((ushort_t*)Cv)[idx] = f2b(v);
                } else if (MODE == 1) {
                    ((ushort_t*)Cv)[idx] = f2b(v + b2f(aux[idx]));
                } else if (MODE == 2) {
                    float h = b2f(aux[idx]);
                    ((ushort_t*)Cv)[idx] = f2b((h / (1.f + __expf(-h))) * v);
                } else if (MODE == 3) {
                    ((ushort_t*)Cv)[(size_t)blockIdx.y * M * N + idx] = f2b(v);
                } else if (MODE == 5) {
                    ((float*)Cv)[idx] = v + aux2[idx];
                } else if (MODE == 6) {
                    if (bn < 2048) {
                        ((ushort_t*)Cv)[(size_t)row * 2048 + col] = f2b(v);
                    } else if (bn < 2560) {
                        ((ushort_t*)C2v)[(size_t)row * 512 + (col - 2048)] = f2b(v);
                    } else {
                        ((ushort_t*)C3v)[(size_t)(col - 2560) * 4096 + row] = f2b(v);
                    }
                }
            }
#undef STG_A
#undef STG_B
#undef DSA
#undef DSB
#undef QUAD
#undef PHASE
}

// ---------------- 128x256 8-phase GEMM (BK=64, 8 waves, 96KB LDS -> grid can hit 256) ----------------
// MODE 1: C = AB + aux (bf16). MODE 5: fp32 C = AB + aux2.
template <int MODE>
__global__ __launch_bounds__(512, 1) void gemm8h(const ushort_t* __restrict__ A,
                                                 const ushort_t* __restrict__ Bt,
                                                 const ushort_t* __restrict__ aux,
                                                 const float* __restrict__ aux2,
                                                 void* __restrict__ Cv,
                                                 int M, int N, int K) {
    __shared__ __align__(16) ushort_t Lds[2 * 24576];  // 96KB: slot = A 16KB + B 32KB
    const int tid = threadIdx.x;
    const int wv = tid >> 6, lane = tid & 63;
    const int l16 = lane & 15, l4 = lane >> 4;
    const int wr = wv >> 2, wc = wv & 3;   // wr: 2 row-halves of 64; wc: 4 col-quarters of 64
    int nwg = gridDim.x;
    int per = nwg >> 3;
    int wg = (blockIdx.x & 7) * per + (blockIdx.x >> 3);
    int mtiles = M >> 7;
    int bx = wg & (mtiles - 1);
    int by = wg / mtiles;
    int bm = bx << 7, bn = by << 8;

    const int sr = tid >> 3;
    const int scol = (((tid & 7) ^ (sr & 7)) << 3);
    const ushort_t* gA = A + (size_t)(bm + sr) * K + scol;
    const ushort_t* gB = Bt + (size_t)(bn + sr) * K + scol;
    ushort_t* ldsw = Lds + wv * 512;

    const int ktiles = K >> 6;
    const int niter = ktiles >> 1;
    const int km = ktiles - 1;

#define HSTG_A(slot, j, kt) gload16(gA + (size_t)((j) * 64) * K + ((kt) << 6), ldsw + (slot) * 24576 + (j) * 4096)
#define HSTG_B(slot, j, kt) gload16(gB + (size_t)((j) * 64) * K + ((kt) << 6), ldsw + (slot) * 24576 + 8192 + (j) * 4096)

    // prologue: t0 complete (6), t1 partial {A0,A1,B0,B1} (4)
    HSTG_A(0, 0, 0); HSTG_A(0, 1, 0);
    HSTG_B(0, 0, 0); HSTG_B(0, 1, 0); HSTG_B(0, 2, 0); HSTG_B(0, 3, 0);
    HSTG_A(1, 0, 1); HSTG_A(1, 1, 1);
    HSTG_B(1, 0, 1); HSTG_B(1, 1, 1);
    vm4();
    asm volatile("" ::: "memory");
    __builtin_amdgcn_s_barrier();

    const int lx = l4 ^ (l16 & 7);
    floatx4 acc[4][4] = {};
    short8 aR[2][2], bR[4][2];

#define HDSA(slot, mh) { _Pragma("unroll") for (int m = 0; m < 2; ++m) { \
    _Pragma("unroll") for (int kk = 0; kk < 2; ++kk) \
      aR[m][kk] = *(const short8*)(Lds + (slot) * 24576 + \
          (wr * 64 + (mh) * 32 + m * 16 + l16) * 64 + ((lx ^ (kk << 2)) << 3)); } }
#define HDSB(slot, nh) { _Pragma("unroll") for (int n = 0; n < 2; ++n) { \
    _Pragma("unroll") for (int kk = 0; kk < 2; ++kk) \
      bR[(nh) * 2 + n][kk] = *(const short8*)(Lds + (slot) * 24576 + 8192 + \
          (wc * 64 + ((nh) * 2 + n) * 16 + l16) * 64 + ((lx ^ (kk << 2)) << 3)); } }
#define HQUAD(mh, nlo) { _Pragma("unroll") for (int m = 0; m < 2; ++m) \
    _Pragma("unroll") for (int n = 0; n < 2; ++n) \
    _Pragma("unroll") for (int kk = 0; kk < 2; ++kk) \
      acc[(mh) * 2 + m][(nlo) + n] = __builtin_amdgcn_mfma_f32_16x16x32_bf16( \
          aR[m][kk], bR[(nlo) + n][kk], acc[(mh) * 2 + m][(nlo) + n], 0, 0, 0); }
#define HPHASE(DS, ST, MH, NLO, VM) { \
    DS; ST; \
    asm volatile("" ::: "memory"); \
    __builtin_amdgcn_s_barrier(); \
    asm volatile("s_waitcnt lgkmcnt(0)" ::: "memory"); \
    __builtin_amdgcn_sched_barrier(0); \
    __builtin_amdgcn_s_setprio(1); \
    HQUAD(MH, NLO); \
    __builtin_amdgcn_s_setprio(0); \
    VM; \
    asm volatile("" ::: "memory"); \
    __builtin_amdgcn_s_barrier(); }

    // slot0 A read in ph1+ph3 -> A t2 staged ph5; slot0 B read ph1-2 -> B t2 staged ph3-4.
    // slot1 A read ph5+ph7 -> A t3 staged ph8; slot1 B read ph5-6 -> B t3 staged ph7 (+next ph1).
    for (int it = 0; it < niter; ++it) {
        int t1 = 2 * it + 1;
        int t2 = (2 * it + 2) & km;
        int t3 = (2 * it + 3) & km;
        HPHASE({ HDSA(0, 0); HDSB(0, 0); }, { HSTG_B(1, 2, t1); HSTG_B(1, 3, t1); }, 0, 0, );
        HPHASE({ HDSB(0, 1); },             { },                                     0, 2, );
        HPHASE({ HDSA(0, 1); },             { HSTG_B(0, 0, t2); HSTG_B(0, 1, t2); }, 1, 2, );
        HPHASE({ },                         { HSTG_B(0, 2, t2); HSTG_B(0, 3, t2); }, 1, 0, vm4(); );
        HPHASE({ HDSA(1, 0); HDSB(1, 0); }, { HSTG_A(0, 0, t2); HSTG_A(0, 1, t2); }, 0, 0, );
        HPHASE({ HDSB(1, 1); },             { },                                     0, 2, );
        HPHASE({ HDSA(1, 1); },             { HSTG_B(1, 0, t3); HSTG_B(1, 1, t3); }, 1, 2, );
        HPHASE({ },                         { HSTG_A(1, 0, t3); HSTG_A(1, 1, t3); }, 1, 0, vm4(); );
    }

#pragma unroll
    for (int mi = 0; mi < 4; ++mi)
#pragma unroll
        for (int ni = 0; ni < 4; ++ni)
#pragma unroll
            for (int r = 0; r < 4; ++r) {
                int row = bm + wr * 64 + mi * 16 + l4 * 4 + r;
                int col = bn + wc * 64 + ni * 16 + l16;
                size_t idx = (size_t)row * N + col;
                float v = acc[mi][ni][r];
                if (MODE == 1) ((ushort_t*)Cv)[idx] = f2b(v + b2f(aux[idx]));
                else if (MODE == 5) ((float*)Cv)[idx] = v + aux2[idx];
            }
#undef HSTG_A
#undef HSTG_B
#undef HDSA
#undef HDSB
#undef HQUAD
#undef HPHASE
}

// ---------------- Flash attention (causal, GQA), QB=64, SB=64, balanced pairs, staged O-write ----------------
#define QB 64
#define SB 64

__global__ __launch_bounds__(256, 2) void attn_kernel(const ushort_t* __restrict__ Q,
                                                      const ushort_t* __restrict__ Kb,
                                                      const ushort_t* __restrict__ VbT,
                                                      ushort_t* __restrict__ O, int Tlen) {
    const int D = 2048, KVD = 512, dh = 128;
    const int MTOK = 4096;
    int p = blockIdx.x, h = blockIdx.y, b = blockIdx.z;
    int kv = h >> 2;
    int t = threadIdx.x, wave = t >> 6, lane = t & 63;
    int l16 = lane & 15, l4 = lane >> 4;
    __shared__ __align__(16) ushort_t Ks[SB][dh + 8];
    __shared__ __align__(16) ushort_t Vt[dh][SB + 8];
    __shared__ __align__(16) ushort_t Ps[4][16][SB + 8];
    const float scale = 0.08838834764831845f;
    const ushort_t* Kg = Kb + ((size_t)(b * Tlen) + (t >> 4)) * KVD + kv * dh + (t & 15) * 8;
    const ushort_t* Vg = VbT + (size_t)(kv * dh + (t >> 3)) * MTOK + b * Tlen + (t & 7) * 8;

    for (int side = 0; side < 2; ++side) {
        int qt = side ? p : (31 - p);
        int qbase = qt * QB;
        int qfrag = qbase + wave * 16;
        short8 qf[4];
        const ushort_t* Qrow = Q + ((size_t)(b * Tlen) + qfrag + l16) * D + h * dh;
#pragma unroll
        for (int kk = 0; kk < 4; ++kk) qf[kk] = *(const short8*)(Qrow + kk * 32 + l4 * 8);
        floatx4 o_acc[8] = {};
        float m_r[4], l_r[4];
#pragma unroll
        for (int r = 0; r < 4; ++r) { m_r[r] = -INFINITY; l_r[r] = 0.f; }
        int nst = qt + 1;
        uint4 kreg[4], vreg[4];
#pragma unroll
        for (int p4 = 0; p4 < 4; ++p4) {
            kreg[p4] = *(const uint4*)(Kg + (size_t)(p4 * 16) * KVD);
            vreg[p4] = *(const uint4*)(Vg + (size_t)(p4 * 32) * MTOK);
        }
        for (int st = 0; st < nst; ++st) {
            __syncthreads();
#pragma unroll
            for (int p4 = 0; p4 < 4; ++p4) {
                *(uint4*)(&Ks[(t >> 4) + p4 * 16][(t & 15) * 8]) = kreg[p4];
                *(uint4*)(&Vt[(t >> 3) + p4 * 32][(t & 7) * 8]) = vreg[p4];
            }
            __syncthreads();
            if (st + 1 < nst) {
                size_t off = (size_t)(st + 1) * SB;
#pragma unroll
                for (int p4 = 0; p4 < 4; ++p4) {
                    kreg[p4] = *(const uint4*)(Kg + (off + p4 * 16) * KVD);
                    vreg[p4] = *(const uint4*)(Vg + (size_t)(p4 * 32) * MTOK + off);
                }
            }
            int s0 = st * SB;
            floatx4 sa[4] = {};
            __builtin_amdgcn_s_setprio(1);
#pragma unroll
            for (int ss = 0; ss < 4; ++ss)
#pragma unroll
                for (int kk = 0; kk < 4; ++kk) {
                    short8 kf = *(const short8*)(&Ks[ss * 16 + l16][kk * 32 + l4 * 8]);
                    sa[ss] = __builtin_amdgcn_mfma_f32_16x16x32_bf16(qf[kk], kf, sa[ss], 0, 0, 0);
                }
            __builtin_amdgcn_s_setprio(0);
            float sv[4][4], pmax[4];
#pragma unroll
            for (int r = 0; r < 4; ++r) pmax[r] = -INFINITY;
#pragma unroll
            for (int ss = 0; ss < 4; ++ss) {
                int scol = s0 + ss * 16 + l16;
#pragma unroll
                for (int r = 0; r < 4; ++r) {
                    int qrow = qfrag + l4 * 4 + r;
                    float v = sa[ss][r] * scale;
                    if (scol > qrow) v = -INFINITY;
                    sv[ss][r] = v;
                    pmax[r] = fmaxf(pmax[r], v);
                }
            }
#pragma unroll
            for (int m = 1; m < 16; m <<= 1)
#pragma unroll
                for (int r = 0; r < 4; ++r) pmax[r] = fmaxf(pmax[r], __shfl_xor(pmax[r], m));
            int cflag = 1;
#pragma unroll
            for (int r = 0; r < 4; ++r) cflag &= (pmax[r] <= m_r[r] + 8.f) ? 1 : 0;
            bool skip = __all(cflag);
            float mn[4], rsum[4];
#pragma unroll
            for (int r = 0; r < 4; ++r) {
                mn[r] = skip ? m_r[r] : fmaxf(m_r[r], pmax[r]);
                rsum[r] = 0.f;
            }
#pragma unroll
            for (int ss = 0; ss < 4; ++ss)
#pragma unroll
                for (int r = 0; r < 4; ++r) {
                    float pv = __expf(sv[ss][r] - mn[r]);
                    sv[ss][r] = pv;
                    rsum[r] += pv;
                }
#pragma unroll
            for (int m = 1; m < 16; m <<= 1)
#pragma unroll
                for (int r = 0; r < 4; ++r) rsum[r] += __shfl_xor(rsum[r], m);
            if (skip) {
#pragma unroll
                for (int r = 0; r < 4; ++r) l_r[r] += rsum[r];
            } else {
#pragma unroll
                for (int r = 0; r < 4; ++r) {
                    float esc = __expf(m_r[r] - mn[r]);
                    l_r[r] = l_r[r] * esc + rsum[r];
                    m_r[r] = mn[r];
#pragma unroll
                    for (int c = 0; c < 8; ++c) o_acc[c][r] *= esc;
                }
            }
#pragma unroll
            for (int ss = 0; ss < 4; ++ss)
#pragma unroll
                for (int r = 0; r < 4; ++r)
                    Ps[wave][l4 * 4 + r][ss * 16 + l16] = f2b(sv[ss][r]);
            short8 pa[2];
#pragma unroll
            for (int kk = 0; kk < 2; ++kk)
                pa[kk] = *(const short8*)(&Ps[wave][l16][kk * 32 + l4 * 8]);
            __builtin_amdgcn_s_setprio(1);
#pragma unroll
            for (int c = 0; c < 8; ++c)
#pragma unroll
                for (int kk = 0; kk < 2; ++kk) {
                    short8 vf = *(const short8*)(&Vt[c * 16 + l16][kk * 32 + l4 * 8]);
                    o_acc[c] = __builtin_amdgcn_mfma_f32_16x16x32_bf16(pa[kk], vf, o_acc[c], 0, 0, 0);
                }
            __builtin_amdgcn_s_setprio(0);
        }
        // ---- staged, coalesced O write (reuse Ks region; full-line stores) ----
        __syncthreads();  // all waves done reading Ks/Vt this side
        ushort_t* Osh = &Ks[0][0];  // [64][136] overlay
#pragma unroll
        for (int c = 0; c < 8; ++c)
#pragma unroll
            for (int r = 0; r < 4; ++r)
                Osh[(wave * 16 + l4 * 4 + r) * 136 + c * 16 + l16] = f2b(o_acc[c][r] / l_r[r]);
        __syncthreads();
        {
            int orow = t >> 2, occ = (t & 3) * 32;
            const ushort_t* srcp = Osh + orow * 136 + occ;
            ushort_t* dstp = O + ((size_t)(b * Tlen) + qbase + orow) * D + h * dh + occ;
#pragma unroll
            for (int k = 0; k < 4; ++k)
                *(uint4*)(dstp + k * 8) = *(const uint4*)(srcp + k * 8);
        }
    }
}

extern "C" void kernel_launch(void* const* d_in, const int* in_sizes, int n_in,
                              void* d_out, int out_size, void* d_ws, size_t ws_size,
                              hipStream_t stream) {
    const float* x   = (const float*)d_in[0];
    const float* n1w = (const float*)d_in[1];
    const float* n2w = (const float*)d_in[2];
    const float* Wq  = (const float*)d_in[3];
    const float* Wk  = (const float*)d_in[4];
    const float* Wv  = (const float*)d_in[5];
    const float* Wo  = (const float*)d_in[6];
    const float* Wc  = (const float*)d_in[7];
    const float* W1  = (const float*)d_in[8];
    const float* W2  = (const float*)d_in[9];
    const float* W3  = (const float*)d_in[10];
    float* out = (float*)d_out;

    const int B = 2, T = 2048, D = 2048, F = 8192, KVD = 512;
    const int M = B * T;  // 4096
    const size_t XD   = (size_t)M * D * 2;
    const size_t XDF  = (size_t)M * D * 4;
    const size_t KVSZ = (size_t)M * KVD * 2;
    const size_t MF   = (size_t)M * F * 2;
    const size_t WDD  = (size_t)D * D * 2;
    const size_t WQKV = (size_t)(D + 2 * KVD) * D * 2;
    const size_t WDF  = (size_t)D * F * 2;

    char* w = (char*)d_ws;
    ushort_t* xn    = (ushort_t*)(w);            // later: p0 (W2 partial 0)
    ushort_t* qtmp  = (ushort_t*)(w + XD);       // later: p1
    ushort_t* qfin  = (ushort_t*)(w + 2 * XD);
    float*    x2f   = (float*)   (w + 3 * XD);
    ushort_t* kbuf  = (ushort_t*)(w + 3 * XD + XDF);
    ushort_t* vbufT = (ushort_t*)(w + 3 * XD + XDF + KVSZ);
    ushort_t* h1    = (ushort_t*)(w + 3 * XD + XDF + 2 * KVSZ);
    char* wt = w + 3 * XD + XDF + 2 * KVSZ + MF;
    ushort_t* WqkvT = (ushort_t*)(wt);
    ushort_t* WcT   = (ushort_t*)(wt + WQKV);
    ushort_t* WoT   = (ushort_t*)(wt + WQKV + WDD);
    ushort_t* W1T   = (ushort_t*)(wt + WQKV + 2 * WDD);
    ushort_t* W3T   = (ushort_t*)(wt + WQKV + 2 * WDD + WDF);
    ushort_t* W2T   = (ushort_t*)(wt + WQKV + 2 * WDD + 2 * WDF);

    dim3 blk(256);
    dim3 blk8(512);

    transpose_w<<<dim3(D / 64, D / 64), blk, 0, stream>>>(Wq, WqkvT, D, D);
    transpose_w<<<dim3(D / 64, KVD / 64), blk, 0, stream>>>(Wk, WqkvT + (size_t)2048 * D, D, KVD);
    transpose_w<<<dim3(D / 64, KVD / 64), blk, 0, stream>>>(Wv, WqkvT + (size_t)2560 * D, D, KVD);
    transpose_w<<<dim3(D / 64, D / 64), blk, 0, stream>>>(Wc, WcT, D, D);
    transpose_w<<<dim3(D / 64, D / 64), blk, 0, stream>>>(Wo, WoT, D, D);
    transpose_w<<<dim3(D / 64, F / 64), blk, 0, stream>>>(W1, W1T, D, F);
    transpose_w<<<dim3(D / 64, F / 64), blk, 0, stream>>>(W3, W3T, D, F);
    transpose_w<<<dim3(F / 64, D / 64), blk, 0, stream>>>(W2, W2T, F, D);

    rmsnorm_kernel<<<M, blk, 0, stream>>>(x, n1w, xn, D);
    // merged QKV (256^2 engine)
    gemm8<6><<<dim3((M / 256) * (3072 / 256)), blk8, 0, stream>>>(
        xn, WqkvT, nullptr, nullptr, qtmp, kbuf, vbufT, M, 3072, D, D);
    // qfin = qtmp @ Wc + qtmp   (128x256 engine, grid 256 -> full residency)
    gemm8h<1><<<dim3((M / 128) * (D / 256)), blk8, 0, stream>>>(
        qtmp, WcT, qtmp, nullptr, qfin, M, D, D);
    attn_kernel<<<dim3(16, 16, B), blk, 0, stream>>>(qfin, kbuf, vbufT, qtmp, T);
    // x2 = att @ Wo + x  (fp32, 128x256 engine)
    gemm8h<5><<<dim3((M / 128) * (D / 256)), blk8, 0, stream>>>(
        qtmp, WoT, nullptr, x, x2f, M, D, D);
    rmsnorm_kernel<<<M, blk, 0, stream>>>(x2f, n2w, xn, D);
    gemm8<0><<<dim3((M / 256) * (F / 256)), blk8, 0, stream>>>(
        xn, W1T, nullptr, nullptr, h1, nullptr, nullptr, M, F, D, D);
    gemm8<2><<<dim3((M / 256) * (F / 256)), blk8, 0, stream>>>(
        xn, W3T, h1, nullptr, h1, nullptr, nullptr, M, F, D, D);
    gemm8<3><<<dim3((M / 256) * (D / 256), 2), blk8, 0, stream>>>(
        h1, W2T, nullptr, nullptr, xn, nullptr, nullptr, M, D, F / 2, F);
    reduce_out<<<1024, blk, 0, stream>>>(xn, x2f, out, M * D);
}